// Round 1
// baseline (1987.846 us; speedup 1.0000x reference)
//
#include <hip/hip_runtime.h>
#include <stdint.h>
#include <type_traits>

typedef __bf16 bf16_t;
typedef __bf16 bf16x8 __attribute__((ext_vector_type(8)));
typedef __bf16 bf16x4 __attribute__((ext_vector_type(4)));
typedef float  f32x4  __attribute__((ext_vector_type(4)));

union Frag { uint32_t u[4]; bf16x8 v; };
union H4   { uint2 u2; bf16x4 v; };

__device__ __forceinline__ float sigm(float x)   { return 1.0f / (1.0f + __expf(-x)); }
__device__ __forceinline__ float tanhf_(float x) { return 1.0f - 2.0f / (__expf(2.0f * x) + 1.0f); }

// MODE 0: first layer  (x f32 [2048][512][18] in, seq bf16 out)
// MODE 1: middle layer (seq bf16 in, seq bf16 out)
// MODE 2: last layer   (seq bf16 in, last f32 [2048][64] out)
//
// Swapped-operand MFMA: D = gates^T tile [16 gate-rows][16 batch].
//   A = Wh/Wi rows (M=gate-rows, K=units/din), B = h^T / x^T.
//   Wave w owns hidden units [16w, 16w+16) -> 4 M-tiles (i,f,g,o).
//   Lane: batch = lane&15, units u0 = 16w + 4*(lane>>4), regs i=0..3 -> u0+i.
//   Produced h frag (4 bf16/lane) == next step's B-frag half: exchange via
//   lds_h[buf][wave][lane] (b64, conflict-free), B-frag kstep s = waves 2s,2s+1.
template<int MODE>
__global__ __launch_bounds__(256, 1)
void lstm_layer(const float* __restrict__ x0,
                const bf16_t* __restrict__ seq_in,
                bf16_t* __restrict__ seq_out,
                float* __restrict__ last_out,
                const float* __restrict__ Wi,
                const float* __restrict__ Wh,
                const float* __restrict__ bi,
                const float* __restrict__ bh)
{
    const int tile = blockIdx.x;          // batch tile: rows [16*tile, 16*tile+16)
    const int tid  = threadIdx.x;
    const int w    = tid >> 6;            // wave 0..3
    const int lane = tid & 63;
    const int l15  = lane & 15;           // batch col (B-side) / A-row (M-side)
    const int l4   = lane >> 4;           // k-group / row-group

    __shared__ uint2 lds_h[2][4][64];     // [buf][wave][lane] = 4 bf16 h values

    // ---- Wh A-fragments (registers, loop-invariant) ----
    // A[m][k]: row = G*64 + 16w + l15, k = 32s + 4*l4 + j  (j>=4: +16)
    bf16x8 whA[4][2];
#pragma unroll
    for (int G = 0; G < 4; ++G) {
        const float* row = Wh + (size_t)(G * 64 + 16 * w + l15) * 64;
#pragma unroll
        for (int s = 0; s < 2; ++s) {
            const int k0 = 32 * s + 4 * l4;
            f32x4 a = *(const f32x4*)(row + k0);
            f32x4 b = *(const f32x4*)(row + k0 + 16);
            bf16x8 f;
            f[0] = (bf16_t)a[0]; f[1] = (bf16_t)a[1]; f[2] = (bf16_t)a[2]; f[3] = (bf16_t)a[3];
            f[4] = (bf16_t)b[0]; f[5] = (bf16_t)b[1]; f[6] = (bf16_t)b[2]; f[7] = (bf16_t)b[3];
            whA[G][s] = f;
        }
    }

    // ---- Wi A-fragments ----
    constexpr int XS = (MODE == 0) ? 1 : 2;
    bf16x8 wiA[4][XS];
    if constexpr (MODE == 0) {
        // Wi is [256][18]; pad K 18 -> 32 with zeros.
#pragma unroll
        for (int G = 0; G < 4; ++G) {
            const float* row = Wi + (size_t)(G * 64 + 16 * w + l15) * 18;
            bf16x8 f;
            const int k0 = 4 * l4;                       // 0,4,8,12 (k0+3 <= 15 < 18)
            f[0] = (bf16_t)row[k0 + 0]; f[1] = (bf16_t)row[k0 + 1];
            f[2] = (bf16_t)row[k0 + 2]; f[3] = (bf16_t)row[k0 + 3];
            f[4] = (l4 == 0) ? (bf16_t)row[16] : (bf16_t)0.0f;   // k=16
            f[5] = (l4 == 0) ? (bf16_t)row[17] : (bf16_t)0.0f;   // k=17
            f[6] = (bf16_t)0.0f; f[7] = (bf16_t)0.0f;            // k=18,19 pad
            wiA[G][0] = f;
        }
    } else {
#pragma unroll
        for (int G = 0; G < 4; ++G) {
            const float* row = Wi + (size_t)(G * 64 + 16 * w + l15) * 64;
#pragma unroll
            for (int s = 0; s < 2; ++s) {
                const int k0 = 32 * s + 4 * l4;
                f32x4 a = *(const f32x4*)(row + k0);
                f32x4 b = *(const f32x4*)(row + k0 + 16);
                bf16x8 f;
                f[0] = (bf16_t)a[0]; f[1] = (bf16_t)a[1]; f[2] = (bf16_t)a[2]; f[3] = (bf16_t)a[3];
                f[4] = (bf16_t)b[0]; f[5] = (bf16_t)b[1]; f[6] = (bf16_t)b[2]; f[7] = (bf16_t)b[3];
                wiA[G][s] = f;
            }
        }
    }

    // ---- bias (bi + bh), per acc reg: row = G*64 + 16w + 4*l4 + i ----
    f32x4 bias[4];
#pragma unroll
    for (int G = 0; G < 4; ++G) {
        const int r = G * 64 + 16 * w + 4 * l4;
        f32x4 u = *(const f32x4*)(bi + r);
        f32x4 v = *(const f32x4*)(bh + r);
        bias[G] = u + v;
    }

    // ---- state: 4 cells per lane (units u0..u0+3, batch l15) ----
    f32x4 c = {0.0f, 0.0f, 0.0f, 0.0f};

    lds_h[0][w][lane] = make_uint2(0u, 0u);    // h_{-1} = 0
    __syncthreads();

    using xreg_t = typename std::conditional<MODE == 0, float, uint2>::type;
    constexpr int XN = (MODE == 0) ? 8 : 4;
    xreg_t X0[XN], X1[XN];

    auto loadx = [&](int t, xreg_t (&dst)[XN]) {
        if constexpr (MODE == 0) {
            const float* xr = x0 + ((size_t)(tile * 16 + l15)) * (512 * 18) + (size_t)t * 18;
            const int k0 = 4 * l4;
            dst[0] = xr[k0 + 0]; dst[1] = xr[k0 + 1];
            dst[2] = xr[k0 + 2]; dst[3] = xr[k0 + 3];
            dst[4] = (l4 == 0) ? xr[16] : 0.0f;
            dst[5] = (l4 == 0) ? xr[17] : 0.0f;
            dst[6] = 0.0f; dst[7] = 0.0f;
        } else {
            const bf16_t* sb = seq_in + (((size_t)tile * 512 + (size_t)t) * 16 + l15) * 64;
            dst[0] = *(const uint2*)(sb + 4 * l4);        // kstep0 lo (units k0..k0+3)
            dst[1] = *(const uint2*)(sb + 4 * l4 + 16);   // kstep0 hi
            dst[2] = *(const uint2*)(sb + 4 * l4 + 32);   // kstep1 lo
            dst[3] = *(const uint2*)(sb + 4 * l4 + 48);   // kstep1 hi
        }
    };

    auto step = [&](int t, xreg_t (&xc)[XN], xreg_t (&xn)[XN]) {
        loadx((t + 1 < 512) ? t + 1 : t, xn);   // prefetch next x
        const int lb = t & 1;

        f32x4 acc[4];
#pragma unroll
        for (int G = 0; G < 4; ++G) acc[G] = bias[G];

        // ---- x contribution ----
        if constexpr (MODE == 0) {
            bf16x8 f;
#pragma unroll
            for (int j = 0; j < 8; ++j) f[j] = (bf16_t)xc[j];
#pragma unroll
            for (int G = 0; G < 4; ++G)
                acc[G] = __builtin_amdgcn_mfma_f32_16x16x32_bf16(wiA[G][0], f, acc[G], 0, 0, 0);
        } else {
#pragma unroll
            for (int s = 0; s < 2; ++s) {
                Frag xb;
                xb.u[0] = xc[2 * s].x; xb.u[1] = xc[2 * s].y;
                xb.u[2] = xc[2 * s + 1].x; xb.u[3] = xc[2 * s + 1].y;
#pragma unroll
                for (int G = 0; G < 4; ++G)
                    acc[G] = __builtin_amdgcn_mfma_f32_16x16x32_bf16(wiA[G][s], xb.v, acc[G], 0, 0, 0);
            }
        }

        // ---- h contribution (B-frag kstep s = waves 2s, 2s+1) ----
#pragma unroll
        for (int s = 0; s < 2; ++s) {
            uint2 lo = lds_h[lb][2 * s][lane];
            uint2 hi = lds_h[lb][2 * s + 1][lane];
            Frag hb;
            hb.u[0] = lo.x; hb.u[1] = lo.y; hb.u[2] = hi.x; hb.u[3] = hi.y;
#pragma unroll
            for (int G = 0; G < 4; ++G)
                acc[G] = __builtin_amdgcn_mfma_f32_16x16x32_bf16(whA[G][s], hb.v, acc[G], 0, 0, 0);
        }

        // ---- LSTM cell update (f32), 4 cells in-lane ----
        H4 hh;
        f32x4 hf;
#pragma unroll
        for (int i = 0; i < 4; ++i) {
            const float ig = acc[0][i], fg = acc[1][i], gg = acc[2][i], og = acc[3][i];
            const float cn = sigm(fg) * c[i] + sigm(ig) * tanhf_(gg);
            c[i] = cn;
            const float hv = sigm(og) * tanhf_(cn);
            hh.v[i] = (bf16_t)hv;
            hf[i] = hv;
        }

        lds_h[lb ^ 1][w][lane] = hh.u2;

        if constexpr (MODE != 2) {
            bf16_t* o = seq_out + (((size_t)tile * 512 + (size_t)t) * 16 + l15) * 64
                        + 16 * w + 4 * l4;
            *(uint2*)o = hh.u2;
        } else {
            if (t == 511) {
                float* o = last_out + ((size_t)(tile * 16 + l15)) * 64 + 16 * w + 4 * l4;
                *(f32x4*)o = hf;
            }
        }
        __syncthreads();
    };

    loadx(0, X0);
    for (int t = 0; t < 512; t += 2) {
        step(t, X0, X1);
        step(t + 1, X1, X0);
    }
}

// out = relu(last @ W1^T + b1) @ W2^T + b2   (f32, tiny)
__global__ __launch_bounds__(256)
void mlp_head(const float* __restrict__ last,
              const float* __restrict__ W1, const float* __restrict__ b1,
              const float* __restrict__ W2, const float* __restrict__ b2,
              float* __restrict__ out)
{
    __shared__ float sW1[128 * 64];
    __shared__ float sb1[128];
    __shared__ float sW2[3 * 128];
    __shared__ float sb2[4];
    const int tid = threadIdx.x;
    for (int i = tid; i < 128 * 64; i += 256) sW1[i] = W1[i];
    for (int i = tid; i < 128; i += 256) sb1[i] = b1[i];
    for (int i = tid; i < 3 * 128; i += 256) sW2[i] = W2[i];
    if (tid < 3) sb2[tid] = b2[tid];
    __syncthreads();

    const int b = blockIdx.x * 256 + tid;     // 8 blocks * 256 = 2048
    const float* lb = last + (size_t)b * 64;
    float xv[64];
#pragma unroll
    for (int k = 0; k < 64; k += 4) {
        f32x4 v = *(const f32x4*)(lb + k);
        xv[k] = v[0]; xv[k + 1] = v[1]; xv[k + 2] = v[2]; xv[k + 3] = v[3];
    }
    float o0 = sb2[0], o1 = sb2[1], o2 = sb2[2];
    for (int j = 0; j < 128; ++j) {
        float a = sb1[j];
        const float* wr = &sW1[j * 64];
#pragma unroll
        for (int k = 0; k < 64; k += 4) {
            f32x4 wv = *(const f32x4*)(wr + k);
            a += xv[k] * wv[0] + xv[k + 1] * wv[1] + xv[k + 2] * wv[2] + xv[k + 3] * wv[3];
        }
        a = fmaxf(a, 0.0f);
        o0 += a * sW2[0 * 128 + j];
        o1 += a * sW2[1 * 128 + j];
        o2 += a * sW2[2 * 128 + j];
    }
    out[(size_t)b * 3 + 0] = o0;
    out[(size_t)b * 3 + 1] = o1;
    out[(size_t)b * 3 + 2] = o2;
}

extern "C" void kernel_launch(void* const* d_in, const int* in_sizes, int n_in,
                              void* d_out, int out_size, void* d_ws, size_t ws_size,
                              hipStream_t stream)
{
    (void)in_sizes; (void)n_in; (void)out_size; (void)ws_size;

    const float* x   = (const float*)d_in[0];
    const float* Wi0 = (const float*)d_in[1];
    const float* Wh0 = (const float*)d_in[2];
    const float* bi0 = (const float*)d_in[3];
    const float* bh0 = (const float*)d_in[4];
    const float* Wi1 = (const float*)d_in[5];
    const float* Wh1 = (const float*)d_in[6];
    const float* bi1 = (const float*)d_in[7];
    const float* bh1 = (const float*)d_in[8];
    const float* Wi2 = (const float*)d_in[9];
    const float* Wh2 = (const float*)d_in[10];
    const float* bi2 = (const float*)d_in[11];
    const float* bh2 = (const float*)d_in[12];
    const float* Wi3 = (const float*)d_in[13];
    const float* Wh3 = (const float*)d_in[14];
    const float* bi3 = (const float*)d_in[15];
    const float* bh3 = (const float*)d_in[16];
    const float* W1  = (const float*)d_in[17];
    const float* b1  = (const float*)d_in[18];
    const float* W2  = (const float*)d_in[19];
    const float* b2  = (const float*)d_in[20];

    // ws layout: bufA (128 MiB) | bufB (128 MiB) | last (512 KiB f32)
    char* ws = (char*)d_ws;
    bf16_t* bufA = (bf16_t*)(ws);
    bf16_t* bufB = (bf16_t*)(ws + (size_t)134217728);
    float*  last = (float*)(ws + (size_t)268435456);

    dim3 grid(128), blk(256);
    lstm_layer<0><<<grid, blk, 0, stream>>>(x, nullptr, bufA, nullptr, Wi0, Wh0, bi0, bh0);
    lstm_layer<1><<<grid, blk, 0, stream>>>(nullptr, bufA, bufB, nullptr, Wi1, Wh1, bi1, bh1);
    lstm_layer<1><<<grid, blk, 0, stream>>>(nullptr, bufB, bufA, nullptr, Wi2, Wh2, bi2, bh2);
    lstm_layer<2><<<grid, blk, 0, stream>>>(nullptr, bufA, nullptr, last, Wi3, Wh3, bi3, bh3);
    mlp_head<<<dim3(8), blk, 0, stream>>>(last, W1, b1, W2, b2, (float*)d_out);
}

// Round 2
// 1590.545 us; speedup vs baseline: 1.2498x; 1.2498x over previous
//
#include <hip/hip_runtime.h>
#include <stdint.h>

typedef __bf16 bf16_t;
typedef __bf16 bf16x8 __attribute__((ext_vector_type(8)));
typedef float  f32x4  __attribute__((ext_vector_type(4)));

union Frag { uint32_t u[4]; bf16x8 v; };

struct WPtrs {
    const float* Wi[4];
    const float* Wh[4];
    const float* bi[4];
    const float* bh[4];
};

__device__ __forceinline__ float sigm(float x) {
    return __fdividef(1.0f, 1.0f + __expf(-x));           // v_exp + v_rcp path
}
__device__ __forceinline__ float tanh_(float x) {
    return 1.0f - __fdividef(2.0f, __expf(2.0f * x) + 1.0f);
}

// Fused 4-layer LSTM, layer-pipelined across waves.
// Grid: 256 blocks (batch tiles of 8 rows, cols 8..15 of the MFMA N=16 are pad).
// Block: 512 threads = 8 waves; wave w: layer l = w>>1, unit-half hf = w&1
// (units [32*hf, 32*hf+32) = global unit-tiles ut in {2hf, 2hf+1}).
// Phase p: wave of layer l computes t = p - l. One barrier per phase.
// h exchange: D-frag(col=l15,row=4*l4+i) == B-frag(n=l15,k=4*l4+j[+16]) identity,
// verified on HW in round 1: lds_h[buf][layer][ut][lane] uint2 (4 bf16 units).
__global__ __launch_bounds__(512, 2)
void lstm_fused(const float* __restrict__ x0, float* __restrict__ last_out, WPtrs wp)
{
    const int tile = blockIdx.x;            // 8-batch tile, 256 tiles
    const int tid  = threadIdx.x;
    const int w    = tid >> 6;
    const int lane = tid & 63;
    const int l15  = lane & 15;
    const int l4   = lane >> 4;
    const int l    = w >> 1;                // layer 0..3
    const int hf   = w & 1;                 // unit half

    __shared__ uint2 lds_h[2][4][4][64];    // [buf][layer][ut][lane], 16 KB
    __shared__ float lds_bias[4][256];      // bi+bh per layer, 4 KB

    // stage biases (broadcast-read later, saves 32 VGPR/lane)
    for (int i = tid; i < 4 * 256; i += 512) {
        const int ly = i >> 8, idx = i & 255;
        lds_bias[ly][idx] = wp.bi[ly][idx] + wp.bh[ly][idx];
    }
    // zero h buffers (h_{-1} = 0 for every layer)
    for (int i = tid; i < 2 * 4 * 4 * 64; i += 512)
        ((uint2*)lds_h)[i] = make_uint2(0u, 0u);

    const float* Wi = wp.Wi[l];
    const float* Wh = wp.Wh[l];

    // ---- weight A-fragments (loop-invariant registers) ----
    // A-frag lane map (HW-verified r1): row = l15, k = 32*s + 4*l4 + j (+16 for j>=4)
    bf16x8 whA[4][2][2];   // [gate][u_local][kstep]
    bf16x8 wiA[4][2][2];   // l==0 uses [.][.][0] only (K=18 padded to 32)
#pragma unroll
    for (int G = 0; G < 4; ++G) {
#pragma unroll
        for (int u = 0; u < 2; ++u) {
            const int row = G * 64 + 16 * (2 * hf + u) + l15;
            const float* r = Wh + (size_t)row * 64;
#pragma unroll
            for (int s = 0; s < 2; ++s) {
                f32x4 a = *(const f32x4*)(r + 32 * s + 4 * l4);
                f32x4 b = *(const f32x4*)(r + 32 * s + 4 * l4 + 16);
                bf16x8 f;
                f[0] = (bf16_t)a[0]; f[1] = (bf16_t)a[1]; f[2] = (bf16_t)a[2]; f[3] = (bf16_t)a[3];
                f[4] = (bf16_t)b[0]; f[5] = (bf16_t)b[1]; f[6] = (bf16_t)b[2]; f[7] = (bf16_t)b[3];
                whA[G][u][s] = f;
            }
            if (l == 0) {
                const float* ri = Wi + (size_t)row * 18;
                const int k0 = 4 * l4;
                bf16x8 f;
                f[0] = (bf16_t)ri[k0 + 0]; f[1] = (bf16_t)ri[k0 + 1];
                f[2] = (bf16_t)ri[k0 + 2]; f[3] = (bf16_t)ri[k0 + 3];
                f[4] = (l4 == 0) ? (bf16_t)ri[16] : (bf16_t)0.0f;
                f[5] = (l4 == 0) ? (bf16_t)ri[17] : (bf16_t)0.0f;
                f[6] = (bf16_t)0.0f; f[7] = (bf16_t)0.0f;
                wiA[G][u][0] = f;
            } else {
                const float* ri = Wi + (size_t)row * 64;
#pragma unroll
                for (int s = 0; s < 2; ++s) {
                    f32x4 a = *(const f32x4*)(ri + 32 * s + 4 * l4);
                    f32x4 b = *(const f32x4*)(ri + 32 * s + 4 * l4 + 16);
                    bf16x8 f;
                    f[0] = (bf16_t)a[0]; f[1] = (bf16_t)a[1]; f[2] = (bf16_t)a[2]; f[3] = (bf16_t)a[3];
                    f[4] = (bf16_t)b[0]; f[5] = (bf16_t)b[1]; f[6] = (bf16_t)b[2]; f[7] = (bf16_t)b[3];
                    wiA[G][u][s] = f;
                }
            }
        }
    }

    // ---- x prefetch (layer-0 waves only), depth 2 ----
    float xs[2][6];
    const int   xbatch = tile * 8 + (l15 < 8 ? l15 : 7);   // pad cols duplicate row 7
    const float* xrow  = x0 + (size_t)xbatch * (512 * 18);
    auto loadx = [&](int t, float* dst) {
        const float* xr = xrow + t * 18;
        const int k0 = 4 * l4;
        dst[0] = xr[k0 + 0]; dst[1] = xr[k0 + 1];
        dst[2] = xr[k0 + 2]; dst[3] = xr[k0 + 3];
        dst[4] = (l4 == 0) ? xr[16] : 0.0f;
        dst[5] = (l4 == 0) ? xr[17] : 0.0f;
    };
    if (l == 0) { loadx(0, xs[0]); loadx(1, xs[1]); }

    f32x4 c[2] = {{0.f,0.f,0.f,0.f},{0.f,0.f,0.f,0.f}};    // cell state, 8 cells/lane

    __syncthreads();

    const float* biasL = &lds_bias[l][0];

    for (int p = 0; p < 512 + 3; ++p) {
        const int t  = p - l;
        const int br = (p & 1) ^ 1;      // read buffer (written in phase p-1)
        const int bw = p & 1;            // write buffer

        if (t >= 0 && t < 512) {
            f32x4 acc[4][2];
#pragma unroll
            for (int G = 0; G < 4; ++G)
#pragma unroll
                for (int u = 0; u < 2; ++u)
                    acc[G][u] = *(const f32x4*)(biasL + G * 64 + 16 * (2 * hf + u) + 4 * l4);

            // ---- x contribution ----
            if (l == 0) {
                const float* cs = xs[t & 1];
                bf16x8 f;
                f[0] = (bf16_t)cs[0]; f[1] = (bf16_t)cs[1];
                f[2] = (bf16_t)cs[2]; f[3] = (bf16_t)cs[3];
                f[4] = (bf16_t)cs[4]; f[5] = (bf16_t)cs[5];
                f[6] = (bf16_t)0.0f;  f[7] = (bf16_t)0.0f;
#pragma unroll
                for (int G = 0; G < 4; ++G)
#pragma unroll
                    for (int u = 0; u < 2; ++u)
                        acc[G][u] = __builtin_amdgcn_mfma_f32_16x16x32_bf16(wiA[G][u][0], f, acc[G][u], 0, 0, 0);
                const int tn = (t + 2 < 512) ? t + 2 : t;   // prefetch 2 ahead
                loadx(tn, xs[t & 1]);
            } else {
#pragma unroll
                for (int s = 0; s < 2; ++s) {
                    uint2 lo = lds_h[br][l - 1][2 * s][lane];
                    uint2 hi = lds_h[br][l - 1][2 * s + 1][lane];
                    Frag xb; xb.u[0] = lo.x; xb.u[1] = lo.y; xb.u[2] = hi.x; xb.u[3] = hi.y;
#pragma unroll
                    for (int G = 0; G < 4; ++G)
#pragma unroll
                        for (int u = 0; u < 2; ++u)
                            acc[G][u] = __builtin_amdgcn_mfma_f32_16x16x32_bf16(wiA[G][u][s], xb.v, acc[G][u], 0, 0, 0);
                }
            }

            // ---- h contribution (own layer, t-1) ----
#pragma unroll
            for (int s = 0; s < 2; ++s) {
                uint2 lo = lds_h[br][l][2 * s][lane];
                uint2 hi = lds_h[br][l][2 * s + 1][lane];
                Frag hb; hb.u[0] = lo.x; hb.u[1] = lo.y; hb.u[2] = hi.x; hb.u[3] = hi.y;
#pragma unroll
                for (int G = 0; G < 4; ++G)
#pragma unroll
                    for (int u = 0; u < 2; ++u)
                        acc[G][u] = __builtin_amdgcn_mfma_f32_16x16x32_bf16(whA[G][u][s], hb.v, acc[G][u], 0, 0, 0);
            }

            // ---- cell update: 8 cells/lane (2 ut x 4 rows) ----
            uint2 hh[2];
#pragma unroll
            for (int u = 0; u < 2; ++u) {
                union { uint2 u2; bf16_t b[4]; } pk;
                f32x4 hv;
#pragma unroll
                for (int i = 0; i < 4; ++i) {
                    const float ig = sigm(acc[0][u][i]);
                    const float fg = sigm(acc[1][u][i]);
                    const float gg = tanh_(acc[2][u][i]);
                    const float og = sigm(acc[3][u][i]);
                    const float cn = fg * c[u][i] + ig * gg;
                    c[u][i] = cn;
                    const float h = og * tanh_(cn);
                    pk.b[i] = (bf16_t)h;
                    hv[i] = h;
                }
                hh[u] = pk.u2;
                if (l == 3 && t == 511 && l15 < 8) {
                    float* o = last_out + ((size_t)(tile * 8 + l15)) * 64
                               + 16 * (2 * hf + u) + 4 * l4;
                    *(f32x4*)o = hv;
                }
            }
            lds_h[bw][l][2 * hf + 0][lane] = hh[0];
            lds_h[bw][l][2 * hf + 1][lane] = hh[1];
        }
        __syncthreads();
    }
}

// out = relu(last @ W1^T + b1) @ W2^T + b2   (f32, tiny)
__global__ __launch_bounds__(256)
void mlp_head(const float* __restrict__ last,
              const float* __restrict__ W1, const float* __restrict__ b1,
              const float* __restrict__ W2, const float* __restrict__ b2,
              float* __restrict__ out)
{
    __shared__ float sW1[128 * 64];
    __shared__ float sb1[128];
    __shared__ float sW2[3 * 128];
    __shared__ float sb2[4];
    const int tid = threadIdx.x;
    for (int i = tid; i < 128 * 64; i += 256) sW1[i] = W1[i];
    for (int i = tid; i < 128; i += 256) sb1[i] = b1[i];
    for (int i = tid; i < 3 * 128; i += 256) sW2[i] = W2[i];
    if (tid < 3) sb2[tid] = b2[tid];
    __syncthreads();

    const int b = blockIdx.x * 256 + tid;     // 8 blocks * 256 = 2048
    const float* lb = last + (size_t)b * 64;
    float xv[64];
#pragma unroll
    for (int k = 0; k < 64; k += 4) {
        f32x4 v = *(const f32x4*)(lb + k);
        xv[k] = v[0]; xv[k + 1] = v[1]; xv[k + 2] = v[2]; xv[k + 3] = v[3];
    }
    float o0 = sb2[0], o1 = sb2[1], o2 = sb2[2];
    for (int j = 0; j < 128; ++j) {
        float a = sb1[j];
        const float* wr = &sW1[j * 64];
#pragma unroll
        for (int k = 0; k < 64; k += 4) {
            f32x4 wv = *(const f32x4*)(wr + k);
            a += xv[k] * wv[0] + xv[k + 1] * wv[1] + xv[k + 2] * wv[2] + xv[k + 3] * wv[3];
        }
        a = fmaxf(a, 0.0f);
        o0 += a * sW2[0 * 128 + j];
        o1 += a * sW2[1 * 128 + j];
        o2 += a * sW2[2 * 128 + j];
    }
    out[(size_t)b * 3 + 0] = o0;
    out[(size_t)b * 3 + 1] = o1;
    out[(size_t)b * 3 + 2] = o2;
}

extern "C" void kernel_launch(void* const* d_in, const int* in_sizes, int n_in,
                              void* d_out, int out_size, void* d_ws, size_t ws_size,
                              hipStream_t stream)
{
    (void)in_sizes; (void)n_in; (void)out_size; (void)ws_size;

    const float* x = (const float*)d_in[0];
    WPtrs wp;
    for (int l = 0; l < 4; ++l) {
        wp.Wi[l] = (const float*)d_in[1 + 4 * l + 0];
        wp.Wh[l] = (const float*)d_in[1 + 4 * l + 1];
        wp.bi[l] = (const float*)d_in[1 + 4 * l + 2];
        wp.bh[l] = (const float*)d_in[1 + 4 * l + 3];
    }
    const float* W1 = (const float*)d_in[17];
    const float* b1 = (const float*)d_in[18];
    const float* W2 = (const float*)d_in[19];
    const float* b2 = (const float*)d_in[20];

    float* last = (float*)d_ws;                 // 2048*64 f32 = 512 KiB

    lstm_fused<<<dim3(256), dim3(512), 0, stream>>>(x, last, wp);
    mlp_head<<<dim3(8), dim3(256), 0, stream>>>(last, W1, b1, W2, b2, (float*)d_out);
}

// Round 4
// 1275.813 us; speedup vs baseline: 1.5581x; 1.2467x over previous
//
#include <hip/hip_runtime.h>
#include <stdint.h>

typedef __bf16 bf16_t;
typedef __bf16 bf16x8 __attribute__((ext_vector_type(8)));
typedef float  f32x4  __attribute__((ext_vector_type(4)));

union Frag { uint32_t u[4]; bf16x8 v; };

struct WPtrs {
    const float* Wi[4];
    const float* Wh[4];
    const float* bi[4];
    const float* bh[4];
};

__device__ __forceinline__ float sigm(float x)  { return __fdividef(1.0f, 1.0f + __expf(-x)); }
__device__ __forceinline__ float tanh_(float x) { return 1.0f - __fdividef(2.0f, __expf(2.0f * x) + 1.0f); }

// Half-swap within each 16-lane DPP row: lane i <-> lane i^8.
// row_ror:8 (0x128): rotate by 8 in a 16-lane row == xor-8 permutation,
// direction-proof (ror8 == rol8), all source lanes valid (no bound_ctrl issues).
// (r3 bug: row_shl:8 moves data the WRONG way — dst[i]=src[i+8].)
__device__ __forceinline__ float dpp_halfswap(float x) {
    int i = __float_as_int(x);
    int r = __builtin_amdgcn_update_dpp(i, i, 0x128 /*row_ror:8*/, 0xF, 0xF, false);
    return __int_as_float(r);
}

// Fused 4-layer LSTM, layer-pipelined across 16 waves.
// Grid: 256 blocks (batch tiles of 8; MFMA N=16 cols 8..15 are pad, but pad
// lanes are repurposed for the cell update via DPP half-swap redistribution).
// Block: 1024 threads = 16 waves; wave w: layer l = w>>2, unit-quarter uq = w&3
// (units [16*uq, 16*uq+16)).
// Phase p: wave of layer l computes t = p - l. One barrier per phase.
// h exchange (HW-verified r1/r2): D-frag(col=l15,row=4*l4+i) == B-frag identity;
// lds_h[buf][layer][ut][lane] uint2 = h units (16ut+4*l4+{0..3}) for col l15.
// Cols 8..15 slots stay ZERO forever (pad batch columns).
__global__ __launch_bounds__(1024, 4)
void lstm_fused(const float* __restrict__ x0, float* __restrict__ last_out, WPtrs wp)
{
    const int tile = blockIdx.x;            // 8-batch tile, 256 tiles
    const int tid  = threadIdx.x;
    const int w    = tid >> 6;
    const int lane = tid & 63;
    const int l15  = lane & 15;
    const int l4   = lane >> 4;
    const int l    = w >> 2;                // layer 0..3
    const int uq   = w & 3;                 // unit quarter (= ut index)
    const bool hiH = (l15 >= 8);
    const int  col = l15 & 7;               // real batch col this lane's cells use

    __shared__ uint2 lds_h[2][4][4][64];    // [buf][layer][ut][lane], 16 KB

    for (int i = tid; i < 2 * 4 * 4 * 64; i += 1024)
        ((uint2*)lds_h)[i] = make_uint2(0u, 0u);

    const float* Wi = wp.Wi[l];
    const float* Wh = wp.Wh[l];

    // ---- weight A-fragments (loop-invariant registers) ----
    // A-frag lane map (HW-verified): row = base + l15, k = 32*s + 4*l4 + j (+16 for j>=4)
    bf16x8 whA[4][2];       // [gate][kstep]
    bf16x8 wiA[4][2];
#pragma unroll
    for (int G = 0; G < 4; ++G) {
        const int row = G * 64 + 16 * uq + l15;
        const float* r = Wh + (size_t)row * 64;
#pragma unroll
        for (int s = 0; s < 2; ++s) {
            f32x4 a = *(const f32x4*)(r + 32 * s + 4 * l4);
            f32x4 b = *(const f32x4*)(r + 32 * s + 4 * l4 + 16);
            bf16x8 f;
            f[0] = (bf16_t)a[0]; f[1] = (bf16_t)a[1]; f[2] = (bf16_t)a[2]; f[3] = (bf16_t)a[3];
            f[4] = (bf16_t)b[0]; f[5] = (bf16_t)b[1]; f[6] = (bf16_t)b[2]; f[7] = (bf16_t)b[3];
            whA[G][s] = f;
        }
        if (l == 0) {
            const float* ri = Wi + (size_t)row * 18;     // K=18 padded to 32
            const int k0 = 4 * l4;
            bf16x8 f;
            f[0] = (bf16_t)ri[k0 + 0]; f[1] = (bf16_t)ri[k0 + 1];
            f[2] = (bf16_t)ri[k0 + 2]; f[3] = (bf16_t)ri[k0 + 3];
            f[4] = (l4 == 0) ? (bf16_t)ri[16] : (bf16_t)0.0f;
            f[5] = (l4 == 0) ? (bf16_t)ri[17] : (bf16_t)0.0f;
            f[6] = (bf16_t)0.0f; f[7] = (bf16_t)0.0f;
            wiA[G][0] = f;
            wiA[G][1] = f;   // unused, keep defined
        } else {
            const float* ri = Wi + (size_t)row * 64;
#pragma unroll
            for (int s = 0; s < 2; ++s) {
                f32x4 a = *(const f32x4*)(ri + 32 * s + 4 * l4);
                f32x4 b = *(const f32x4*)(ri + 32 * s + 4 * l4 + 16);
                bf16x8 f;
                f[0] = (bf16_t)a[0]; f[1] = (bf16_t)a[1]; f[2] = (bf16_t)a[2]; f[3] = (bf16_t)a[3];
                f[4] = (bf16_t)b[0]; f[5] = (bf16_t)b[1]; f[6] = (bf16_t)b[2]; f[7] = (bf16_t)b[3];
                wiA[G][s] = f;
            }
        }
    }

    // ---- bias in VGPRs; used as the C operand of the first MFMA ----
    f32x4 bias[4];
#pragma unroll
    for (int G = 0; G < 4; ++G) {
        const int r = G * 64 + 16 * uq + 4 * l4;
        f32x4 u = *(const f32x4*)(wp.bi[l] + r);
        f32x4 v = *(const f32x4*)(wp.bh[l] + r);
        bias[G] = u + v;
    }

    // ---- x prefetch (layer-0 waves only), depth 2 ----
    float xs[2][6];
    const int    xbatch = tile * 8 + (hiH ? 7 : col);     // pad lanes duplicate row 7
    const float* xrow   = x0 + (size_t)xbatch * (512 * 18);
    auto loadx = [&](int t, float* dst) {
        const float* xr = xrow + t * 18;
        const int k0 = 4 * l4;
        dst[0] = xr[k0 + 0]; dst[1] = xr[k0 + 1];
        dst[2] = xr[k0 + 2]; dst[3] = xr[k0 + 3];
        dst[4] = (l4 == 0) ? xr[16] : 0.0f;
        dst[5] = (l4 == 0) ? xr[17] : 0.0f;
    };
    if (l == 0) { loadx(0, xs[0]); loadx(1, xs[1]); }

    // cell state: 2 real cells/lane -> (i = hiH?{2,3}:{0,1}, col)
    float c0 = 0.0f, c1 = 0.0f;

    __syncthreads();

    for (int p = 0; p < 512 + 3; ++p) {
        const int t = p - l;
        if (t >= 0 && t < 512) {
            const int br = (p & 1) ^ 1;      // buffer written at phase p-1
            const int bw = p & 1;

            f32x4 acc[4];

            // ---- x contribution (bias folded into first MFMA's C) ----
            if (l == 0) {
                const float* cs = xs[t & 1];
                bf16x8 f;
                f[0] = (bf16_t)cs[0]; f[1] = (bf16_t)cs[1];
                f[2] = (bf16_t)cs[2]; f[3] = (bf16_t)cs[3];
                f[4] = (bf16_t)cs[4]; f[5] = (bf16_t)cs[5];
                f[6] = (bf16_t)0.0f;  f[7] = (bf16_t)0.0f;
#pragma unroll
                for (int G = 0; G < 4; ++G)
                    acc[G] = __builtin_amdgcn_mfma_f32_16x16x32_bf16(wiA[G][0], f, bias[G], 0, 0, 0);
                const int tn = (t + 2 < 512) ? t + 2 : t;
                loadx(tn, xs[t & 1]);
            } else {
                uint2 lo = lds_h[br][l - 1][0][lane];
                uint2 hi = lds_h[br][l - 1][1][lane];
                Frag b0; b0.u[0] = lo.x; b0.u[1] = lo.y; b0.u[2] = hi.x; b0.u[3] = hi.y;
#pragma unroll
                for (int G = 0; G < 4; ++G)
                    acc[G] = __builtin_amdgcn_mfma_f32_16x16x32_bf16(wiA[G][0], b0.v, bias[G], 0, 0, 0);
                lo = lds_h[br][l - 1][2][lane];
                hi = lds_h[br][l - 1][3][lane];
                Frag b1; b1.u[0] = lo.x; b1.u[1] = lo.y; b1.u[2] = hi.x; b1.u[3] = hi.y;
#pragma unroll
                for (int G = 0; G < 4; ++G)
                    acc[G] = __builtin_amdgcn_mfma_f32_16x16x32_bf16(wiA[G][1], b1.v, acc[G], 0, 0, 0);
            }

            // ---- h contribution (own layer, t-1) ----
            {
                uint2 lo = lds_h[br][l][0][lane];
                uint2 hi = lds_h[br][l][1][lane];
                Frag b0; b0.u[0] = lo.x; b0.u[1] = lo.y; b0.u[2] = hi.x; b0.u[3] = hi.y;
#pragma unroll
                for (int G = 0; G < 4; ++G)
                    acc[G] = __builtin_amdgcn_mfma_f32_16x16x32_bf16(whA[G][0], b0.v, acc[G], 0, 0, 0);
                lo = lds_h[br][l][2][lane];
                hi = lds_h[br][l][3][lane];
                Frag b1; b1.u[0] = lo.x; b1.u[1] = lo.y; b1.u[2] = hi.x; b1.u[3] = hi.y;
#pragma unroll
                for (int G = 0; G < 4; ++G)
                    acc[G] = __builtin_amdgcn_mfma_f32_16x16x32_bf16(whA[G][1], b1.v, acc[G], 0, 0, 0);
            }

            // ---- DPP half-swap: every lane ends with 2 REAL cells ----
            // lanes l15<8: gates i={0,1} of own col; lanes l15>=8: gates i={2,3}
            // of col l15-8 (received from the lo partner via lane i^8).
            float g0[4], g1[4];
#pragma unroll
            for (int G = 0; G < 4; ++G) {
                const float s2 = dpp_halfswap(acc[G][2]);
                const float s3 = dpp_halfswap(acc[G][3]);
                g0[G] = hiH ? s2 : acc[G][0];
                g1[G] = hiH ? s3 : acc[G][1];
            }

            // ---- cell update: 2 cells ----
            const float cA = sigm(g0[1]) * c0 + sigm(g0[0]) * tanh_(g0[2]);
            const float cB = sigm(g1[1]) * c1 + sigm(g1[0]) * tanh_(g1[2]);
            c0 = cA; c1 = cB;
            const float hA = sigm(g0[3]) * tanh_(cA);
            const float hB = sigm(g1[3]) * tanh_(cB);

            // ---- h writeback: one b32 (2 bf16) per lane; pad col slots never written ----
            union { uint32_t u; bf16_t b[2]; } pk;
            pk.b[0] = (bf16_t)hA; pk.b[1] = (bf16_t)hB;
            uint32_t* slot = (uint32_t*)&lds_h[bw][l][uq][16 * l4 + col];
            slot[hiH ? 1 : 0] = pk.u;

            if (l == 3 && t == 511) {
                float* o = last_out + ((size_t)(tile * 8 + col)) * 64
                           + 16 * uq + 4 * l4 + (hiH ? 2 : 0);
                *(float2*)o = make_float2(hA, hB);
            }
        }
        __syncthreads();
    }
}

// out = relu(last @ W1^T + b1) @ W2^T + b2   (f32, tiny)
__global__ __launch_bounds__(256)
void mlp_head(const float* __restrict__ last,
              const float* __restrict__ W1, const float* __restrict__ b1,
              const float* __restrict__ W2, const float* __restrict__ b2,
              float* __restrict__ out)
{
    __shared__ float sW1[128 * 64];
    __shared__ float sb1[128];
    __shared__ float sW2[3 * 128];
    __shared__ float sb2[4];
    const int tid = threadIdx.x;
    for (int i = tid; i < 128 * 64; i += 256) sW1[i] = W1[i];
    for (int i = tid; i < 128; i += 256) sb1[i] = b1[i];
    for (int i = tid; i < 3 * 128; i += 256) sW2[i] = W2[i];
    if (tid < 3) sb2[tid] = b2[tid];
    __syncthreads();

    const int b = blockIdx.x * 256 + tid;     // 8 blocks * 256 = 2048
    const float* lb = last + (size_t)b * 64;
    float xv[64];
#pragma unroll
    for (int k = 0; k < 64; k += 4) {
        f32x4 v = *(const f32x4*)(lb + k);
        xv[k] = v[0]; xv[k + 1] = v[1]; xv[k + 2] = v[2]; xv[k + 3] = v[3];
    }
    float o0 = sb2[0], o1 = sb2[1], o2 = sb2[2];
    for (int j = 0; j < 128; ++j) {
        float a = sb1[j];
        const float* wr = &sW1[j * 64];
#pragma unroll
        for (int k = 0; k < 64; k += 4) {
            f32x4 wv = *(const f32x4*)(wr + k);
            a += xv[k] * wv[0] + xv[k + 1] * wv[1] + xv[k + 2] * wv[2] + xv[k + 3] * wv[3];
        }
        a = fmaxf(a, 0.0f);
        o0 += a * sW2[0 * 128 + j];
        o1 += a * sW2[1 * 128 + j];
        o2 += a * sW2[2 * 128 + j];
    }
    out[(size_t)b * 3 + 0] = o0;
    out[(size_t)b * 3 + 1] = o1;
    out[(size_t)b * 3 + 2] = o2;
}

extern "C" void kernel_launch(void* const* d_in, const int* in_sizes, int n_in,
                              void* d_out, int out_size, void* d_ws, size_t ws_size,
                              hipStream_t stream)
{
    (void)in_sizes; (void)n_in; (void)out_size; (void)ws_size;

    const float* x = (const float*)d_in[0];
    WPtrs wp;
    for (int l = 0; l < 4; ++l) {
        wp.Wi[l] = (const float*)d_in[1 + 4 * l + 0];
        wp.Wh[l] = (const float*)d_in[1 + 4 * l + 1];
        wp.bi[l] = (const float*)d_in[1 + 4 * l + 2];
        wp.bh[l] = (const float*)d_in[1 + 4 * l + 3];
    }
    const float* W1 = (const float*)d_in[17];
    const float* b1 = (const float*)d_in[18];
    const float* W2 = (const float*)d_in[19];
    const float* b2 = (const float*)d_in[20];

    float* last = (float*)d_ws;                 // 2048*64 f32 = 512 KiB

    lstm_fused<<<dim3(256), dim3(1024), 0, stream>>>(x, last, wp);
    mlp_head<<<dim3(8), dim3(256), 0, stream>>>(last, W1, b1, W2, b2, (float*)d_out);
}

// Round 5
// 1009.370 us; speedup vs baseline: 1.9694x; 1.2640x over previous
//
#include <hip/hip_runtime.h>
#include <stdint.h>

typedef __bf16 bf16_t;
typedef __bf16 bf16x8 __attribute__((ext_vector_type(8)));
typedef float  f32x4  __attribute__((ext_vector_type(4)));

union Frag { uint32_t u[4]; bf16x8 v; };

struct WPtrs {
    const float* Wi[4];
    const float* Wh[4];
    const float* bi[4];
    const float* bh[4];
};

#define LOG2E 1.44269504088896340736f

// Gate pre-activations arrive PRE-SCALED by log2e (i,f,o) / 2*log2e (g),
// folded into the bf16 weight fragments + biases at build time.
// v_exp_f32 computes 2^x; '-x' is a free VOP input modifier.
__device__ __forceinline__ float sigm2(float xs) {            // xs = x*log2e
    return __builtin_amdgcn_rcpf(1.0f + __builtin_amdgcn_exp2f(-xs));
}
__device__ __forceinline__ float tanh2(float ys) {            // ys = x*2*log2e
    return 1.0f - 2.0f * __builtin_amdgcn_rcpf(__builtin_amdgcn_exp2f(ys) + 1.0f);
}
__device__ __forceinline__ float tanhc(float c) {             // unscaled input
    return tanh2(c * (2.0f * LOG2E));
}

// Half-swap within each 16-lane DPP row: lane i <-> lane i^8 (row_ror:8).
__device__ __forceinline__ float dpp_halfswap(float x) {
    int i = __float_as_int(x);
    int r = __builtin_amdgcn_update_dpp(i, i, 0x128 /*row_ror:8*/, 0xF, 0xF, false);
    return __int_as_float(r);
}

// Fused 4-layer LSTM, layer-pipelined across 16 waves (structure HW-verified r4).
// Grid 256 blocks = batch tiles of 8 (MFMA N=16, cols 8..15 pad; pad lanes
// repurposed via DPP half-swap so all 64 lanes compute 2 REAL cells).
// Block 1024 thr = 16 waves; wave w: layer l=w>>2, unit-quarter uq=w&3.
// Phase p: layer l computes t=p-l; 1 barrier/phase; lds_h double-buffered.
// r5 changes vs r4: (1) phase loop unrolled x2 with NAMED x buffers
// (r4's xs[t&1] runtime index spilled to scratch: WRITE_SIZE 42MB, rule #20);
// (2) log2e folded into gate weights -> exp2-native activations.
__global__ __launch_bounds__(1024, 4)
void lstm_fused(const float* __restrict__ x0, float* __restrict__ last_out, WPtrs wp)
{
    const int tile = blockIdx.x;
    const int tid  = threadIdx.x;
    const int w    = tid >> 6;
    const int lane = tid & 63;
    const int l15  = lane & 15;
    const int l4   = lane >> 4;
    const int l    = w >> 2;
    const int uq   = w & 3;
    const bool hiH = (l15 >= 8);
    const int  col = l15 & 7;

    __shared__ uint2 lds_h[2][4][4][64];    // [buf][layer][ut][lane], 16 KB

    for (int i = tid; i < 2 * 4 * 4 * 64; i += 1024)
        ((uint2*)lds_h)[i] = make_uint2(0u, 0u);

    const float* Wi = wp.Wi[l];
    const float* Wh = wp.Wh[l];

    // per-gate prescale: i,f,o -> log2e ; g -> 2*log2e
    const float gs[4] = {LOG2E, LOG2E, 2.0f * LOG2E, LOG2E};

    // ---- weight A-fragments (loop-invariant registers) ----
    bf16x8 whA[4][2];
    bf16x8 wiA[4][2];
#pragma unroll
    for (int G = 0; G < 4; ++G) {
        const float sc = gs[G];
        const int row = G * 64 + 16 * uq + l15;
        const float* r = Wh + (size_t)row * 64;
#pragma unroll
        for (int s = 0; s < 2; ++s) {
            f32x4 a = *(const f32x4*)(r + 32 * s + 4 * l4);
            f32x4 b = *(const f32x4*)(r + 32 * s + 4 * l4 + 16);
            bf16x8 f;
            f[0] = (bf16_t)(a[0] * sc); f[1] = (bf16_t)(a[1] * sc);
            f[2] = (bf16_t)(a[2] * sc); f[3] = (bf16_t)(a[3] * sc);
            f[4] = (bf16_t)(b[0] * sc); f[5] = (bf16_t)(b[1] * sc);
            f[6] = (bf16_t)(b[2] * sc); f[7] = (bf16_t)(b[3] * sc);
            whA[G][s] = f;
        }
        if (l == 0) {
            const float* ri = Wi + (size_t)row * 18;     // K=18 padded to 32
            const int k0 = 4 * l4;
            bf16x8 f;
            f[0] = (bf16_t)(ri[k0 + 0] * sc); f[1] = (bf16_t)(ri[k0 + 1] * sc);
            f[2] = (bf16_t)(ri[k0 + 2] * sc); f[3] = (bf16_t)(ri[k0 + 3] * sc);
            f[4] = (l4 == 0) ? (bf16_t)(ri[16] * sc) : (bf16_t)0.0f;
            f[5] = (l4 == 0) ? (bf16_t)(ri[17] * sc) : (bf16_t)0.0f;
            f[6] = (bf16_t)0.0f; f[7] = (bf16_t)0.0f;
            wiA[G][0] = f;
            wiA[G][1] = f;
        } else {
            const float* ri = Wi + (size_t)row * 64;
#pragma unroll
            for (int s = 0; s < 2; ++s) {
                f32x4 a = *(const f32x4*)(ri + 32 * s + 4 * l4);
                f32x4 b = *(const f32x4*)(ri + 32 * s + 4 * l4 + 16);
                bf16x8 f;
                f[0] = (bf16_t)(a[0] * sc); f[1] = (bf16_t)(a[1] * sc);
                f[2] = (bf16_t)(a[2] * sc); f[3] = (bf16_t)(a[3] * sc);
                f[4] = (bf16_t)(b[0] * sc); f[5] = (bf16_t)(b[1] * sc);
                f[6] = (bf16_t)(b[2] * sc); f[7] = (bf16_t)(b[3] * sc);
                wiA[G][s] = f;
            }
        }
    }

    // ---- bias in VGPRs (prescaled); C operand of the first MFMA ----
    f32x4 bias[4];
#pragma unroll
    for (int G = 0; G < 4; ++G) {
        const int r = G * 64 + 16 * uq + 4 * l4;
        f32x4 u = *(const f32x4*)(wp.bi[l] + r);
        f32x4 v = *(const f32x4*)(wp.bh[l] + r);
        bias[G] = (u + v) * gs[G];
    }

    // ---- x prefetch (layer-0 waves), depth 2, STATIC buffers ----
    float xsA[6], xsB[6];
    const int    xbatch = tile * 8 + (hiH ? 7 : col);
    const float* xrow   = x0 + (size_t)xbatch * (512 * 18);
    auto loadx = [&](int t, float (&dst)[6]) {
        const float* xr = xrow + t * 18;
        const int k0 = 4 * l4;
        dst[0] = xr[k0 + 0]; dst[1] = xr[k0 + 1];
        dst[2] = xr[k0 + 2]; dst[3] = xr[k0 + 3];
        dst[4] = (l4 == 0) ? xr[16] : 0.0f;
        dst[5] = (l4 == 0) ? xr[17] : 0.0f;
    };
    if (l == 0) { loadx(0, xsA); loadx(1, xsB); }

    float c0 = 0.0f, c1 = 0.0f;     // 2 real cells/lane

    __syncthreads();

    auto phase = [&](int p, float (&cs)[6]) {
        const int t = p - l;
        if (t >= 0 && t < 512) {
            const int br = (p & 1) ^ 1;
            const int bw = p & 1;

            f32x4 acc[4];

            // ---- x contribution (bias folded into first MFMA's C) ----
            if (l == 0) {
                bf16x8 f;
                f[0] = (bf16_t)cs[0]; f[1] = (bf16_t)cs[1];
                f[2] = (bf16_t)cs[2]; f[3] = (bf16_t)cs[3];
                f[4] = (bf16_t)cs[4]; f[5] = (bf16_t)cs[5];
                f[6] = (bf16_t)0.0f;  f[7] = (bf16_t)0.0f;
#pragma unroll
                for (int G = 0; G < 4; ++G)
                    acc[G] = __builtin_amdgcn_mfma_f32_16x16x32_bf16(wiA[G][0], f, bias[G], 0, 0, 0);
                const int tn = (t + 2 < 512) ? t + 2 : t;   // prefetch 2 ahead
                loadx(tn, cs);
            } else {
                uint2 lo = lds_h[br][l - 1][0][lane];
                uint2 hi = lds_h[br][l - 1][1][lane];
                Frag b0; b0.u[0] = lo.x; b0.u[1] = lo.y; b0.u[2] = hi.x; b0.u[3] = hi.y;
#pragma unroll
                for (int G = 0; G < 4; ++G)
                    acc[G] = __builtin_amdgcn_mfma_f32_16x16x32_bf16(wiA[G][0], b0.v, bias[G], 0, 0, 0);
                lo = lds_h[br][l - 1][2][lane];
                hi = lds_h[br][l - 1][3][lane];
                Frag b1; b1.u[0] = lo.x; b1.u[1] = lo.y; b1.u[2] = hi.x; b1.u[3] = hi.y;
#pragma unroll
                for (int G = 0; G < 4; ++G)
                    acc[G] = __builtin_amdgcn_mfma_f32_16x16x32_bf16(wiA[G][1], b1.v, acc[G], 0, 0, 0);
            }

            // ---- h contribution (own layer, t-1) ----
            {
                uint2 lo = lds_h[br][l][0][lane];
                uint2 hi = lds_h[br][l][1][lane];
                Frag b0; b0.u[0] = lo.x; b0.u[1] = lo.y; b0.u[2] = hi.x; b0.u[3] = hi.y;
#pragma unroll
                for (int G = 0; G < 4; ++G)
                    acc[G] = __builtin_amdgcn_mfma_f32_16x16x32_bf16(whA[G][0], b0.v, acc[G], 0, 0, 0);
                lo = lds_h[br][l][2][lane];
                hi = lds_h[br][l][3][lane];
                Frag b1; b1.u[0] = lo.x; b1.u[1] = lo.y; b1.u[2] = hi.x; b1.u[3] = hi.y;
#pragma unroll
                for (int G = 0; G < 4; ++G)
                    acc[G] = __builtin_amdgcn_mfma_f32_16x16x32_bf16(whA[G][1], b1.v, acc[G], 0, 0, 0);
            }

            // ---- DPP half-swap: every lane gets 2 REAL cells ----
            float g0[4], g1[4];
#pragma unroll
            for (int G = 0; G < 4; ++G) {
                const float s2 = dpp_halfswap(acc[G][2]);
                const float s3 = dpp_halfswap(acc[G][3]);
                g0[G] = hiH ? s2 : acc[G][0];
                g1[G] = hiH ? s3 : acc[G][1];
            }

            // ---- cell update (prescaled gates) ----
            const float cA = sigm2(g0[1]) * c0 + sigm2(g0[0]) * tanh2(g0[2]);
            const float cB = sigm2(g1[1]) * c1 + sigm2(g1[0]) * tanh2(g1[2]);
            c0 = cA; c1 = cB;
            const float hA = sigm2(g0[3]) * tanhc(cA);
            const float hB = sigm2(g1[3]) * tanhc(cB);

            // ---- h writeback: one b32 per lane; pad col slots never written ----
            union { uint32_t u; bf16_t b[2]; } pk;
            pk.b[0] = (bf16_t)hA; pk.b[1] = (bf16_t)hB;
            uint32_t* slot = (uint32_t*)&lds_h[bw][l][uq][16 * l4 + col];
            slot[hiH ? 1 : 0] = pk.u;

            if (l == 3 && t == 511) {
                float* o = last_out + ((size_t)(tile * 8 + col)) * 64
                           + 16 * uq + 4 * l4 + (hiH ? 2 : 0);
                *(float2*)o = make_float2(hA, hB);
            }
        }
        __syncthreads();
    };

    // 515 phases needed (t=511 for l=3 at p=514); rounded up to 516.
    for (int p = 0; p < 516; p += 2) {
        phase(p,     xsA);      // l=0: t=p   (even) -> xsA
        phase(p + 1, xsB);      // l=0: t=p+1 (odd)  -> xsB
    }
}

// out = relu(last @ W1^T + b1) @ W2^T + b2   (f32, tiny)
__global__ __launch_bounds__(256)
void mlp_head(const float* __restrict__ last,
              const float* __restrict__ W1, const float* __restrict__ b1,
              const float* __restrict__ W2, const float* __restrict__ b2,
              float* __restrict__ out)
{
    __shared__ float sW1[128 * 64];
    __shared__ float sb1[128];
    __shared__ float sW2[3 * 128];
    __shared__ float sb2[4];
    const int tid = threadIdx.x;
    for (int i = tid; i < 128 * 64; i += 256) sW1[i] = W1[i];
    for (int i = tid; i < 128; i += 256) sb1[i] = b1[i];
    for (int i = tid; i < 3 * 128; i += 256) sW2[i] = W2[i];
    if (tid < 3) sb2[tid] = b2[tid];
    __syncthreads();

    const int b = blockIdx.x * 256 + tid;
    const float* lb = last + (size_t)b * 64;
    float xv[64];
#pragma unroll
    for (int k = 0; k < 64; k += 4) {
        f32x4 v = *(const f32x4*)(lb + k);
        xv[k] = v[0]; xv[k + 1] = v[1]; xv[k + 2] = v[2]; xv[k + 3] = v[3];
    }
    float o0 = sb2[0], o1 = sb2[1], o2 = sb2[2];
    for (int j = 0; j < 128; ++j) {
        float a = sb1[j];
        const float* wr = &sW1[j * 64];
#pragma unroll
        for (int k = 0; k < 64; k += 4) {
            f32x4 wv = *(const f32x4*)(wr + k);
            a += xv[k] * wv[0] + xv[k + 1] * wv[1] + xv[k + 2] * wv[2] + xv[k + 3] * wv[3];
        }
        a = fmaxf(a, 0.0f);
        o0 += a * sW2[0 * 128 + j];
        o1 += a * sW2[1 * 128 + j];
        o2 += a * sW2[2 * 128 + j];
    }
    out[(size_t)b * 3 + 0] = o0;
    out[(size_t)b * 3 + 1] = o1;
    out[(size_t)b * 3 + 2] = o2;
}

extern "C" void kernel_launch(void* const* d_in, const int* in_sizes, int n_in,
                              void* d_out, int out_size, void* d_ws, size_t ws_size,
                              hipStream_t stream)
{
    (void)in_sizes; (void)n_in; (void)out_size; (void)ws_size;

    const float* x = (const float*)d_in[0];
    WPtrs wp;
    for (int l = 0; l < 4; ++l) {
        wp.Wi[l] = (const float*)d_in[1 + 4 * l + 0];
        wp.Wh[l] = (const float*)d_in[1 + 4 * l + 1];
        wp.bi[l] = (const float*)d_in[1 + 4 * l + 2];
        wp.bh[l] = (const float*)d_in[1 + 4 * l + 3];
    }
    const float* W1 = (const float*)d_in[17];
    const float* b1 = (const float*)d_in[18];
    const float* W2 = (const float*)d_in[19];
    const float* b2 = (const float*)d_in[20];

    float* last = (float*)d_ws;                 // 2048*64 f32 = 512 KiB

    lstm_fused<<<dim3(256), dim3(1024), 0, stream>>>(x, last, wp);
    mlp_head<<<dim3(8), dim3(256), 0, stream>>>(last, W1, b1, W2, b2, (float*)d_out);
}

// Round 6
// 601.166 us; speedup vs baseline: 3.3067x; 1.6790x over previous
//
#include <hip/hip_runtime.h>
#include <stdint.h>

typedef __bf16 bf16_t;
typedef __bf16 bf16x8 __attribute__((ext_vector_type(8)));
typedef float  f32x4  __attribute__((ext_vector_type(4)));

union Frag { uint32_t u[4]; bf16x8 v; };

struct WPtrs {
    const float* Wi[4];
    const float* Wh[4];
    const float* bi[4];
    const float* bh[4];
};

#define LOG2E 1.44269504088896340736f

// Gate pre-activations arrive PRE-SCALED by log2e (i,f,o) / 2*log2e (g),
// folded into the bf16 weight fragments + biases at build time.
__device__ __forceinline__ float sigm2(float xs) {            // xs = x*log2e
    return __builtin_amdgcn_rcpf(1.0f + __builtin_amdgcn_exp2f(-xs));
}
__device__ __forceinline__ float tanh2(float ys) {            // ys = x*2*log2e
    return 1.0f - 2.0f * __builtin_amdgcn_rcpf(__builtin_amdgcn_exp2f(ys) + 1.0f);
}
__device__ __forceinline__ float tanhc(float c) {             // unscaled input
    return tanh2(c * (2.0f * LOG2E));
}

// Half-swap within each 16-lane DPP row: lane i <-> lane i^8 (row_ror:8).
__device__ __forceinline__ float dpp_halfswap(float x) {
    int i = __float_as_int(x);
    int r = __builtin_amdgcn_update_dpp(i, i, 0x128 /*row_ror:8*/, 0xF, 0xF, false);
    return __int_as_float(r);
}

// Fused 4-layer LSTM, layer-pipelined across 16 waves (structure HW-verified r4/r5).
// Grid 256 blocks = batch tiles of 8 (MFMA N=16, cols 8..15 pad; pad lanes
// repurposed via DPP half-swap so all 64 lanes compute 2 REAL cells).
// Block 1024 thr = 16 waves; wave w: layer l=w>>2, unit-quarter uq=w&3.
// Phase p: layer l computes t=p-l; 1 barrier/phase; lds_h double-buffered.
//
// r6 vs r5 — ONE goal: fit the 128-reg unified cap (16-wave block) to kill
// the persistent ~37 dword/thread spill (WRITE_SIZE 39MB, scratch reloads
// on the per-phase critical path):
//  (1) bias 16 regs -> 8: post-DPP each lane only consumes gate rows
//      4*l4+(hiH?2:0) and +1; keep exactly those 8 prescaled scalars and
//      add AFTER the swap (MFMA C starts at zero).
//  (2) x prefetch 12 regs -> 8: pack to bf16x8 fragments at load time.
// Budget: weights 64 + bias 8 + acc 16 + x 8 + temps ~25 = ~121 < 128.
__global__ __launch_bounds__(1024, 4)
void lstm_fused(const float* __restrict__ x0, float* __restrict__ last_out, WPtrs wp)
{
    const int tile = blockIdx.x;
    const int tid  = threadIdx.x;
    const int w    = tid >> 6;
    const int lane = tid & 63;
    const int l15  = lane & 15;
    const int l4   = lane >> 4;
    const int l    = w >> 2;
    const int uq   = w & 3;
    const bool hiH = (l15 >= 8);
    const int  col = l15 & 7;

    __shared__ uint2 lds_h[2][4][4][64];    // [buf][layer][ut][lane], 16 KB

    for (int i = tid; i < 2 * 4 * 4 * 64; i += 1024)
        ((uint2*)lds_h)[i] = make_uint2(0u, 0u);

    const float* Wi = wp.Wi[l];
    const float* Wh = wp.Wh[l];

    // per-gate prescale: i,f,o -> log2e ; g -> 2*log2e
    const float gs[4] = {LOG2E, LOG2E, 2.0f * LOG2E, LOG2E};

    // ---- weight A-fragments (loop-invariant registers) ----
    // A-frag lane map (HW-verified): row = base + l15, k = 32*s + 4*l4 + j (+16 for j>=4)
    bf16x8 whA[4][2];
    bf16x8 wiA[4][2];
#pragma unroll
    for (int G = 0; G < 4; ++G) {
        const float sc = gs[G];
        const int row = G * 64 + 16 * uq + l15;
        const float* r = Wh + (size_t)row * 64;
#pragma unroll
        for (int s = 0; s < 2; ++s) {
            f32x4 a = *(const f32x4*)(r + 32 * s + 4 * l4);
            f32x4 b = *(const f32x4*)(r + 32 * s + 4 * l4 + 16);
            bf16x8 f;
            f[0] = (bf16_t)(a[0] * sc); f[1] = (bf16_t)(a[1] * sc);
            f[2] = (bf16_t)(a[2] * sc); f[3] = (bf16_t)(a[3] * sc);
            f[4] = (bf16_t)(b[0] * sc); f[5] = (bf16_t)(b[1] * sc);
            f[6] = (bf16_t)(b[2] * sc); f[7] = (bf16_t)(b[3] * sc);
            whA[G][s] = f;
        }
        if (l == 0) {
            const float* ri = Wi + (size_t)row * 18;     // K=18 padded to 32
            const int k0 = 4 * l4;
            bf16x8 f;
            f[0] = (bf16_t)(ri[k0 + 0] * sc); f[1] = (bf16_t)(ri[k0 + 1] * sc);
            f[2] = (bf16_t)(ri[k0 + 2] * sc); f[3] = (bf16_t)(ri[k0 + 3] * sc);
            f[4] = (l4 == 0) ? (bf16_t)(ri[16] * sc) : (bf16_t)0.0f;
            f[5] = (l4 == 0) ? (bf16_t)(ri[17] * sc) : (bf16_t)0.0f;
            f[6] = (bf16_t)0.0f; f[7] = (bf16_t)0.0f;
            wiA[G][0] = f;
            wiA[G][1] = f;
        } else {
            const float* ri = Wi + (size_t)row * 64;
#pragma unroll
            for (int s = 0; s < 2; ++s) {
                f32x4 a = *(const f32x4*)(ri + 32 * s + 4 * l4);
                f32x4 b = *(const f32x4*)(ri + 32 * s + 4 * l4 + 16);
                bf16x8 f;
                f[0] = (bf16_t)(a[0] * sc); f[1] = (bf16_t)(a[1] * sc);
                f[2] = (bf16_t)(a[2] * sc); f[3] = (bf16_t)(a[3] * sc);
                f[4] = (bf16_t)(b[0] * sc); f[5] = (bf16_t)(b[1] * sc);
                f[6] = (bf16_t)(b[2] * sc); f[7] = (bf16_t)(b[3] * sc);
                wiA[G][s] = f;
            }
        }
    }

    // ---- bias: ONLY the 8 post-swap scalars this lane consumes ----
    // cell A row = 16uq + 4*l4 + (hiH?2:0), cell B row = +1 (prescaled).
    float biasA[4], biasB[4];
#pragma unroll
    for (int G = 0; G < 4; ++G) {
        const int rb = G * 64 + 16 * uq + 4 * l4 + (hiH ? 2 : 0);
        biasA[G] = (wp.bi[l][rb]     + wp.bh[l][rb])     * gs[G];
        biasB[G] = (wp.bi[l][rb + 1] + wp.bh[l][rb + 1]) * gs[G];
    }

    // ---- x prefetch (layer-0 waves), depth 2, packed bf16 fragments ----
    bf16x8 xfA, xfB;
    const int    xbatch = tile * 8 + (hiH ? 7 : col);
    const float* xrow   = x0 + (size_t)xbatch * (512 * 18);
    auto loadx = [&](int t, bf16x8& dst) {
        const float* xr = xrow + t * 18;
        const int k0 = 4 * l4;
        bf16x8 f;
        f[0] = (bf16_t)xr[k0 + 0]; f[1] = (bf16_t)xr[k0 + 1];
        f[2] = (bf16_t)xr[k0 + 2]; f[3] = (bf16_t)xr[k0 + 3];
        f[4] = (l4 == 0) ? (bf16_t)xr[16] : (bf16_t)0.0f;
        f[5] = (l4 == 0) ? (bf16_t)xr[17] : (bf16_t)0.0f;
        f[6] = (bf16_t)0.0f; f[7] = (bf16_t)0.0f;
        dst = f;
    };
    if (l == 0) { loadx(0, xfA); loadx(1, xfB); }

    float c0 = 0.0f, c1 = 0.0f;     // 2 real cells/lane

    __syncthreads();

    auto phase = [&](int p, bf16x8& xf) {
        const int t = p - l;
        if (t >= 0 && t < 512) {
            const int br = (p & 1) ^ 1;
            const int bw = p & 1;

            const f32x4 z4 = {0.0f, 0.0f, 0.0f, 0.0f};
            f32x4 acc[4];

            // ---- x contribution (C starts at zero; bias added post-DPP) ----
            if (l == 0) {
#pragma unroll
                for (int G = 0; G < 4; ++G)
                    acc[G] = __builtin_amdgcn_mfma_f32_16x16x32_bf16(wiA[G][0], xf, z4, 0, 0, 0);
                const int tn = (t + 2 < 512) ? t + 2 : t;   // prefetch 2 ahead
                loadx(tn, xf);
            } else {
                uint2 lo = lds_h[br][l - 1][0][lane];
                uint2 hi = lds_h[br][l - 1][1][lane];
                Frag b0; b0.u[0] = lo.x; b0.u[1] = lo.y; b0.u[2] = hi.x; b0.u[3] = hi.y;
#pragma unroll
                for (int G = 0; G < 4; ++G)
                    acc[G] = __builtin_amdgcn_mfma_f32_16x16x32_bf16(wiA[G][0], b0.v, z4, 0, 0, 0);
                lo = lds_h[br][l - 1][2][lane];
                hi = lds_h[br][l - 1][3][lane];
                Frag b1; b1.u[0] = lo.x; b1.u[1] = lo.y; b1.u[2] = hi.x; b1.u[3] = hi.y;
#pragma unroll
                for (int G = 0; G < 4; ++G)
                    acc[G] = __builtin_amdgcn_mfma_f32_16x16x32_bf16(wiA[G][1], b1.v, acc[G], 0, 0, 0);
            }

            // ---- h contribution (own layer, t-1) ----
            {
                uint2 lo = lds_h[br][l][0][lane];
                uint2 hi = lds_h[br][l][1][lane];
                Frag b0; b0.u[0] = lo.x; b0.u[1] = lo.y; b0.u[2] = hi.x; b0.u[3] = hi.y;
#pragma unroll
                for (int G = 0; G < 4; ++G)
                    acc[G] = __builtin_amdgcn_mfma_f32_16x16x32_bf16(whA[G][0], b0.v, acc[G], 0, 0, 0);
                lo = lds_h[br][l][2][lane];
                hi = lds_h[br][l][3][lane];
                Frag b1; b1.u[0] = lo.x; b1.u[1] = lo.y; b1.u[2] = hi.x; b1.u[3] = hi.y;
#pragma unroll
                for (int G = 0; G < 4; ++G)
                    acc[G] = __builtin_amdgcn_mfma_f32_16x16x32_bf16(whA[G][1], b1.v, acc[G], 0, 0, 0);
            }

            // ---- DPP half-swap: every lane gets 2 REAL cells; add bias here ----
            float g0[4], g1[4];
#pragma unroll
            for (int G = 0; G < 4; ++G) {
                const float s2 = dpp_halfswap(acc[G][2]);
                const float s3 = dpp_halfswap(acc[G][3]);
                g0[G] = (hiH ? s2 : acc[G][0]) + biasA[G];
                g1[G] = (hiH ? s3 : acc[G][1]) + biasB[G];
            }

            // ---- cell update (prescaled gates) ----
            const float cA = sigm2(g0[1]) * c0 + sigm2(g0[0]) * tanh2(g0[2]);
            const float cB = sigm2(g1[1]) * c1 + sigm2(g1[0]) * tanh2(g1[2]);
            c0 = cA; c1 = cB;
            const float hA = sigm2(g0[3]) * tanhc(cA);
            const float hB = sigm2(g1[3]) * tanhc(cB);

            // ---- h writeback: one b32 per lane; pad col slots never written ----
            union { uint32_t u; bf16_t b[2]; } pk;
            pk.b[0] = (bf16_t)hA; pk.b[1] = (bf16_t)hB;
            uint32_t* slot = (uint32_t*)&lds_h[bw][l][uq][16 * l4 + col];
            slot[hiH ? 1 : 0] = pk.u;

            if (l == 3 && t == 511) {
                float* o = last_out + ((size_t)(tile * 8 + col)) * 64
                           + 16 * uq + 4 * l4 + (hiH ? 2 : 0);
                *(float2*)o = make_float2(hA, hB);
            }
        }
        __syncthreads();
    };

    // 515 phases needed (t=511 for l=3 at p=514); rounded up to 516.
    for (int p = 0; p < 516; p += 2) {
        phase(p,     xfA);      // l=0: t=p   (even) -> xfA
        phase(p + 1, xfB);      // l=0: t=p+1 (odd)  -> xfB
    }
}

// out = relu(last @ W1^T + b1) @ W2^T + b2   (f32, tiny)
__global__ __launch_bounds__(256)
void mlp_head(const float* __restrict__ last,
              const float* __restrict__ W1, const float* __restrict__ b1,
              const float* __restrict__ W2, const float* __restrict__ b2,
              float* __restrict__ out)
{
    __shared__ float sW1[128 * 64];
    __shared__ float sb1[128];
    __shared__ float sW2[3 * 128];
    __shared__ float sb2[4];
    const int tid = threadIdx.x;
    for (int i = tid; i < 128 * 64; i += 256) sW1[i] = W1[i];
    for (int i = tid; i < 128; i += 256) sb1[i] = b1[i];
    for (int i = tid; i < 3 * 128; i += 256) sW2[i] = W2[i];
    if (tid < 3) sb2[tid] = b2[tid];
    __syncthreads();

    const int b = blockIdx.x * 256 + tid;
    const float* lb = last + (size_t)b * 64;
    float xv[64];
#pragma unroll
    for (int k = 0; k < 64; k += 4) {
        f32x4 v = *(const f32x4*)(lb + k);
        xv[k] = v[0]; xv[k + 1] = v[1]; xv[k + 2] = v[2]; xv[k + 3] = v[3];
    }
    float o0 = sb2[0], o1 = sb2[1], o2 = sb2[2];
    for (int j = 0; j < 128; ++j) {
        float a = sb1[j];
        const float* wr = &sW1[j * 64];
#pragma unroll
        for (int k = 0; k < 64; k += 4) {
            f32x4 wv = *(const f32x4*)(wr + k);
            a += xv[k] * wv[0] + xv[k + 1] * wv[1] + xv[k + 2] * wv[2] + xv[k + 3] * wv[3];
        }
        a = fmaxf(a, 0.0f);
        o0 += a * sW2[0 * 128 + j];
        o1 += a * sW2[1 * 128 + j];
        o2 += a * sW2[2 * 128 + j];
    }
    out[(size_t)b * 3 + 0] = o0;
    out[(size_t)b * 3 + 1] = o1;
    out[(size_t)b * 3 + 2] = o2;
}

extern "C" void kernel_launch(void* const* d_in, const int* in_sizes, int n_in,
                              void* d_out, int out_size, void* d_ws, size_t ws_size,
                              hipStream_t stream)
{
    (void)in_sizes; (void)n_in; (void)out_size; (void)ws_size;

    const float* x = (const float*)d_in[0];
    WPtrs wp;
    for (int l = 0; l < 4; ++l) {
        wp.Wi[l] = (const float*)d_in[1 + 4 * l + 0];
        wp.Wh[l] = (const float*)d_in[1 + 4 * l + 1];
        wp.bi[l] = (const float*)d_in[1 + 4 * l + 2];
        wp.bh[l] = (const float*)d_in[1 + 4 * l + 3];
    }
    const float* W1 = (const float*)d_in[17];
    const float* b1 = (const float*)d_in[18];
    const float* W2 = (const float*)d_in[19];
    const float* b2 = (const float*)d_in[20];

    float* last = (float*)d_ws;                 // 2048*64 f32 = 512 KiB

    lstm_fused<<<dim3(256), dim3(1024), 0, stream>>>(x, last, wp);
    mlp_head<<<dim3(8), dim3(256), 0, stream>>>(last, W1, b1, W2, b2, (float*)d_out);
}

// Round 7
// 599.169 us; speedup vs baseline: 3.3177x; 1.0033x over previous
//
#include <hip/hip_runtime.h>
#include <stdint.h>

typedef __bf16 bf16_t;
typedef __bf16 bf16x8 __attribute__((ext_vector_type(8)));
typedef float  f32x4  __attribute__((ext_vector_type(4)));

union Frag { uint32_t u[4]; bf16x8 v; };

struct WPtrs {
    const float* Wi[4];
    const float* Wh[4];
    const float* bi[4];
    const float* bh[4];
};

#define LOG2E 1.44269504088896340736f

// Gate pre-activations arrive PRE-SCALED by log2e (i,f,o) / 2*log2e (g),
// folded into the bf16 weight fragments + biases at build time.
__device__ __forceinline__ float sigm2(float xs) {            // xs = x*log2e
    return __builtin_amdgcn_rcpf(1.0f + __builtin_amdgcn_exp2f(-xs));
}
__device__ __forceinline__ float tanh2(float ys) {            // ys = x*2*log2e
    return 1.0f - 2.0f * __builtin_amdgcn_rcpf(__builtin_amdgcn_exp2f(ys) + 1.0f);
}
__device__ __forceinline__ float tanhc(float c) {             // unscaled input
    return tanh2(c * (2.0f * LOG2E));
}

// Half-swap within each 16-lane DPP row: lane i <-> lane i^8 (row_ror:8).
__device__ __forceinline__ float dpp_halfswap(float x) {
    int i = __float_as_int(x);
    int r = __builtin_amdgcn_update_dpp(i, i, 0x128 /*row_ror:8*/, 0xF, 0xF, false);
    return __int_as_float(r);
}

// Fused 4-layer LSTM, layer-pipelined across 16 waves (structure HW-verified r4-r6).
// Grid 256 blocks = batch tiles of 8 (MFMA N=16, cols 8..15 pad; pad lanes
// repurposed via DPP half-swap so all 64 lanes compute 2 REAL cells).
// Block 1024 thr = 16 waves; wave w: layer l=w>>2, unit-quarter uq=w&3.
// Phase p: layer l computes t=p-l; 1 barrier/phase; lds_h double-buffered.
//
// r7 vs r6 — ONE change: alias the two layer-0 x-prefetch fragments onto
// wiA[2][1] / wiA[3][1] (dead for l==0: its Wi path is single-kstep; l>0
// never touches x buffers). Frees 8 VGPRs -> demand ~123 < 128-reg unified
// cap (16-wave block), eliminating the last ~3-dword/thread spill whose
// per-phase scratch reload was the critical-path stall (r6: WRITE 13.8MB).
__global__ __launch_bounds__(1024, 4)
void lstm_fused(const float* __restrict__ x0, float* __restrict__ last_out, WPtrs wp)
{
    const int tile = blockIdx.x;
    const int tid  = threadIdx.x;
    const int w    = tid >> 6;
    const int lane = tid & 63;
    const int l15  = lane & 15;
    const int l4   = lane >> 4;
    const int l    = w >> 2;
    const int uq   = w & 3;
    const bool hiH = (l15 >= 8);
    const int  col = l15 & 7;

    __shared__ uint2 lds_h[2][4][4][64];    // [buf][layer][ut][lane], 16 KB

    for (int i = tid; i < 2 * 4 * 4 * 64; i += 1024)
        ((uint2*)lds_h)[i] = make_uint2(0u, 0u);

    const float* Wi = wp.Wi[l];
    const float* Wh = wp.Wh[l];

    // per-gate prescale: i,f,o -> log2e ; g -> 2*log2e
    const float gs[4] = {LOG2E, LOG2E, 2.0f * LOG2E, LOG2E};

    // ---- weight A-fragments (loop-invariant registers) ----
    // A-frag lane map (HW-verified): row = base + l15, k = 32*s + 4*l4 + j (+16 for j>=4)
    bf16x8 whA[4][2];
    bf16x8 wiA[4][2];
#pragma unroll
    for (int G = 0; G < 4; ++G) {
        const float sc = gs[G];
        const int row = G * 64 + 16 * uq + l15;
        const float* r = Wh + (size_t)row * 64;
#pragma unroll
        for (int s = 0; s < 2; ++s) {
            f32x4 a = *(const f32x4*)(r + 32 * s + 4 * l4);
            f32x4 b = *(const f32x4*)(r + 32 * s + 4 * l4 + 16);
            bf16x8 f;
            f[0] = (bf16_t)(a[0] * sc); f[1] = (bf16_t)(a[1] * sc);
            f[2] = (bf16_t)(a[2] * sc); f[3] = (bf16_t)(a[3] * sc);
            f[4] = (bf16_t)(b[0] * sc); f[5] = (bf16_t)(b[1] * sc);
            f[6] = (bf16_t)(b[2] * sc); f[7] = (bf16_t)(b[3] * sc);
            whA[G][s] = f;
        }
        if (l == 0) {
            const float* ri = Wi + (size_t)row * 18;     // K=18 padded to 32
            const int k0 = 4 * l4;
            bf16x8 f;
            f[0] = (bf16_t)(ri[k0 + 0] * sc); f[1] = (bf16_t)(ri[k0 + 1] * sc);
            f[2] = (bf16_t)(ri[k0 + 2] * sc); f[3] = (bf16_t)(ri[k0 + 3] * sc);
            f[4] = (l4 == 0) ? (bf16_t)(ri[16] * sc) : (bf16_t)0.0f;
            f[5] = (l4 == 0) ? (bf16_t)(ri[17] * sc) : (bf16_t)0.0f;
            f[6] = (bf16_t)0.0f; f[7] = (bf16_t)0.0f;
            wiA[G][0] = f;
            wiA[G][1] = f;   // placeholder; [2][1]/[3][1] become x buffers below
        } else {
            const float* ri = Wi + (size_t)row * 64;
#pragma unroll
            for (int s = 0; s < 2; ++s) {
                f32x4 a = *(const f32x4*)(ri + 32 * s + 4 * l4);
                f32x4 b = *(const f32x4*)(ri + 32 * s + 4 * l4 + 16);
                bf16x8 f;
                f[0] = (bf16_t)(a[0] * sc); f[1] = (bf16_t)(a[1] * sc);
                f[2] = (bf16_t)(a[2] * sc); f[3] = (bf16_t)(a[3] * sc);
                f[4] = (bf16_t)(b[0] * sc); f[5] = (bf16_t)(b[1] * sc);
                f[6] = (bf16_t)(b[2] * sc); f[7] = (bf16_t)(b[3] * sc);
                wiA[G][s] = f;
            }
        }
    }

    // ---- bias: ONLY the 8 post-swap scalars this lane consumes ----
    float biasA[4], biasB[4];
#pragma unroll
    for (int G = 0; G < 4; ++G) {
        const int rb = G * 64 + 16 * uq + 4 * l4 + (hiH ? 2 : 0);
        biasA[G] = (wp.bi[l][rb]     + wp.bh[l][rb])     * gs[G];
        biasB[G] = (wp.bi[l][rb + 1] + wp.bh[l][rb + 1]) * gs[G];
    }

    // ---- x prefetch (layer-0 waves), depth 2 ----
    // ALIASED onto wiA[2][1] / wiA[3][1]: dead slots for l==0, untouched by l>0.
    bf16x8& xfA = wiA[2][1];
    bf16x8& xfB = wiA[3][1];
    const int    xbatch = tile * 8 + (hiH ? 7 : col);
    const float* xrow   = x0 + (size_t)xbatch * (512 * 18);
    auto loadx = [&](int t, bf16x8& dst) {
        const float* xr = xrow + t * 18;
        const int k0 = 4 * l4;
        bf16x8 f;
        f[0] = (bf16_t)xr[k0 + 0]; f[1] = (bf16_t)xr[k0 + 1];
        f[2] = (bf16_t)xr[k0 + 2]; f[3] = (bf16_t)xr[k0 + 3];
        f[4] = (l4 == 0) ? (bf16_t)xr[16] : (bf16_t)0.0f;
        f[5] = (l4 == 0) ? (bf16_t)xr[17] : (bf16_t)0.0f;
        f[6] = (bf16_t)0.0f; f[7] = (bf16_t)0.0f;
        dst = f;
    };
    if (l == 0) { loadx(0, xfA); loadx(1, xfB); }

    float c0 = 0.0f, c1 = 0.0f;     // 2 real cells/lane

    __syncthreads();

    auto phase = [&](int p, bf16x8& xf) {
        const int t = p - l;
        if (t >= 0 && t < 512) {
            const int br = (p & 1) ^ 1;
            const int bw = p & 1;

            const f32x4 z4 = {0.0f, 0.0f, 0.0f, 0.0f};
            f32x4 acc[4];

            // ---- x contribution (C starts at zero; bias added post-DPP) ----
            if (l == 0) {
#pragma unroll
                for (int G = 0; G < 4; ++G)
                    acc[G] = __builtin_amdgcn_mfma_f32_16x16x32_bf16(wiA[G][0], xf, z4, 0, 0, 0);
                const int tn = (t + 2 < 512) ? t + 2 : t;   // prefetch 2 ahead
                loadx(tn, xf);
            } else {
                uint2 lo = lds_h[br][l - 1][0][lane];
                uint2 hi = lds_h[br][l - 1][1][lane];
                Frag b0; b0.u[0] = lo.x; b0.u[1] = lo.y; b0.u[2] = hi.x; b0.u[3] = hi.y;
#pragma unroll
                for (int G = 0; G < 4; ++G)
                    acc[G] = __builtin_amdgcn_mfma_f32_16x16x32_bf16(wiA[G][0], b0.v, z4, 0, 0, 0);
                lo = lds_h[br][l - 1][2][lane];
                hi = lds_h[br][l - 1][3][lane];
                Frag b1; b1.u[0] = lo.x; b1.u[1] = lo.y; b1.u[2] = hi.x; b1.u[3] = hi.y;
#pragma unroll
                for (int G = 0; G < 4; ++G)
                    acc[G] = __builtin_amdgcn_mfma_f32_16x16x32_bf16(wiA[G][1], b1.v, acc[G], 0, 0, 0);
            }

            // ---- h contribution (own layer, t-1) ----
            {
                uint2 lo = lds_h[br][l][0][lane];
                uint2 hi = lds_h[br][l][1][lane];
                Frag b0; b0.u[0] = lo.x; b0.u[1] = lo.y; b0.u[2] = hi.x; b0.u[3] = hi.y;
#pragma unroll
                for (int G = 0; G < 4; ++G)
                    acc[G] = __builtin_amdgcn_mfma_f32_16x16x32_bf16(whA[G][0], b0.v, acc[G], 0, 0, 0);
                lo = lds_h[br][l][2][lane];
                hi = lds_h[br][l][3][lane];
                Frag b1; b1.u[0] = lo.x; b1.u[1] = lo.y; b1.u[2] = hi.x; b1.u[3] = hi.y;
#pragma unroll
                for (int G = 0; G < 4; ++G)
                    acc[G] = __builtin_amdgcn_mfma_f32_16x16x32_bf16(whA[G][1], b1.v, acc[G], 0, 0, 0);
            }

            // ---- DPP half-swap: every lane gets 2 REAL cells; add bias here ----
            float g0[4], g1[4];
#pragma unroll
            for (int G = 0; G < 4; ++G) {
                const float s2 = dpp_halfswap(acc[G][2]);
                const float s3 = dpp_halfswap(acc[G][3]);
                g0[G] = (hiH ? s2 : acc[G][0]) + biasA[G];
                g1[G] = (hiH ? s3 : acc[G][1]) + biasB[G];
            }

            // ---- cell update (prescaled gates) ----
            const float cA = sigm2(g0[1]) * c0 + sigm2(g0[0]) * tanh2(g0[2]);
            const float cB = sigm2(g1[1]) * c1 + sigm2(g1[0]) * tanh2(g1[2]);
            c0 = cA; c1 = cB;
            const float hA = sigm2(g0[3]) * tanhc(cA);
            const float hB = sigm2(g1[3]) * tanhc(cB);

            // ---- h writeback: one b32 per lane; pad col slots never written ----
            union { uint32_t u; bf16_t b[2]; } pk;
            pk.b[0] = (bf16_t)hA; pk.b[1] = (bf16_t)hB;
            uint32_t* slot = (uint32_t*)&lds_h[bw][l][uq][16 * l4 + col];
            slot[hiH ? 1 : 0] = pk.u;

            if (l == 3 && t == 511) {
                float* o = last_out + ((size_t)(tile * 8 + col)) * 64
                           + 16 * uq + 4 * l4 + (hiH ? 2 : 0);
                *(float2*)o = make_float2(hA, hB);
            }
        }
        __syncthreads();
    };

    // 515 phases needed (t=511 for l=3 at p=514); rounded up to 516.
    for (int p = 0; p < 516; p += 2) {
        phase(p,     xfA);      // l=0: t=p   (even) -> xfA
        phase(p + 1, xfB);      // l=0: t=p+1 (odd)  -> xfB
    }
}

// out = relu(last @ W1^T + b1) @ W2^T + b2   (f32, tiny)
__global__ __launch_bounds__(256)
void mlp_head(const float* __restrict__ last,
              const float* __restrict__ W1, const float* __restrict__ b1,
              const float* __restrict__ W2, const float* __restrict__ b2,
              float* __restrict__ out)
{
    __shared__ float sW1[128 * 64];
    __shared__ float sb1[128];
    __shared__ float sW2[3 * 128];
    __shared__ float sb2[4];
    const int tid = threadIdx.x;
    for (int i = tid; i < 128 * 64; i += 256) sW1[i] = W1[i];
    for (int i = tid; i < 128; i += 256) sb1[i] = b1[i];
    for (int i = tid; i < 3 * 128; i += 256) sW2[i] = W2[i];
    if (tid < 3) sb2[tid] = b2[tid];
    __syncthreads();

    const int b = blockIdx.x * 256 + tid;
    const float* lb = last + (size_t)b * 64;
    float xv[64];
#pragma unroll
    for (int k = 0; k < 64; k += 4) {
        f32x4 v = *(const f32x4*)(lb + k);
        xv[k] = v[0]; xv[k + 1] = v[1]; xv[k + 2] = v[2]; xv[k + 3] = v[3];
    }
    float o0 = sb2[0], o1 = sb2[1], o2 = sb2[2];
    for (int j = 0; j < 128; ++j) {
        float a = sb1[j];
        const float* wr = &sW1[j * 64];
#pragma unroll
        for (int k = 0; k < 64; k += 4) {
            f32x4 wv = *(const f32x4*)(wr + k);
            a += xv[k] * wv[0] + xv[k + 1] * wv[1] + xv[k + 2] * wv[2] + xv[k + 3] * wv[3];
        }
        a = fmaxf(a, 0.0f);
        o0 += a * sW2[0 * 128 + j];
        o1 += a * sW2[1 * 128 + j];
        o2 += a * sW2[2 * 128 + j];
    }
    out[(size_t)b * 3 + 0] = o0;
    out[(size_t)b * 3 + 1] = o1;
    out[(size_t)b * 3 + 2] = o2;
}

extern "C" void kernel_launch(void* const* d_in, const int* in_sizes, int n_in,
                              void* d_out, int out_size, void* d_ws, size_t ws_size,
                              hipStream_t stream)
{
    (void)in_sizes; (void)n_in; (void)out_size; (void)ws_size;

    const float* x = (const float*)d_in[0];
    WPtrs wp;
    for (int l = 0; l < 4; ++l) {
        wp.Wi[l] = (const float*)d_in[1 + 4 * l + 0];
        wp.Wh[l] = (const float*)d_in[1 + 4 * l + 1];
        wp.bi[l] = (const float*)d_in[1 + 4 * l + 2];
        wp.bh[l] = (const float*)d_in[1 + 4 * l + 3];
    }
    const float* W1 = (const float*)d_in[17];
    const float* b1 = (const float*)d_in[18];
    const float* W2 = (const float*)d_in[19];
    const float* b2 = (const float*)d_in[20];

    float* last = (float*)d_ws;                 // 2048*64 f32 = 512 KiB

    lstm_fused<<<dim3(256), dim3(1024), 0, stream>>>(x, last, wp);
    mlp_head<<<dim3(8), dim3(256), 0, stream>>>(last, W1, b1, W2, b2, (float*)d_out);
}

// Round 8
// 581.268 us; speedup vs baseline: 3.4198x; 1.0308x over previous
//
#include <hip/hip_runtime.h>
#include <stdint.h>

typedef __bf16 bf16_t;
typedef __bf16 bf16x8 __attribute__((ext_vector_type(8)));
typedef float  f32x4  __attribute__((ext_vector_type(4)));

union Frag { uint32_t u[4]; bf16x8 v; };

struct WPtrs {
    const float* Wi[4];
    const float* Wh[4];
    const float* bi[4];
    const float* bh[4];
};

#define LOG2E 1.44269504088896340736f

// Gate pre-activations arrive PRE-SCALED: i,f,o by log2e; g by 2*log2e
// (folded into bf16 weight fragments + biases at build time).
// Shared-rcp cell algebra (r8): one rcp per c-update, one per h-update.
//   c' = sigma(f)*c + sigma(i)*tanh(g)
//      = [c*(1+ei)*(Eg+1) + (Eg-1)*(1+ef)] / [(1+ef)*(1+ei)*(Eg+1)]
//   h  = sigma(o)*tanh(c') = (Ec-1) / [(1+eo)*(Ec+1)]
__device__ __forceinline__ float cell_c(float gi, float gf, float gg, float c) {
    const float ef = __builtin_amdgcn_exp2f(-gf);
    const float ei = __builtin_amdgcn_exp2f(-gi);
    const float Eg = __builtin_amdgcn_exp2f(gg);
    const float pf = 1.0f + ef, pi = 1.0f + ei;
    const float pg = Eg + 1.0f, mg = Eg - 1.0f;
    const float num = c * pi * pg + mg * pf;
    const float den = pf * pi * pg;
    return num * __builtin_amdgcn_rcpf(den);
}
__device__ __forceinline__ float cell_h(float go, float c) {
    const float Ec = __builtin_amdgcn_exp2f(c * (2.0f * LOG2E));
    const float eo = __builtin_amdgcn_exp2f(-go);
    const float num = Ec - 1.0f;
    const float den = (1.0f + eo) * (Ec + 1.0f);
    return num * __builtin_amdgcn_rcpf(den);
}

// Half-swap within each 16-lane DPP row: lane i <-> lane i^8 (row_ror:8).
__device__ __forceinline__ float dpp_halfswap(float x) {
    int i = __float_as_int(x);
    int r = __builtin_amdgcn_update_dpp(i, i, 0x128 /*row_ror:8*/, 0xF, 0xF, false);
    return __int_as_float(r);
}

// Fused 4-layer LSTM, layer-pipelined across 16 waves (structure HW-verified r4-r7).
// Grid 256 blocks = batch tiles of 8 (MFMA N=16, cols 8..15 pad; pad lanes
// repurposed via DPP half-swap so all 64 lanes compute 2 REAL cells).
// Block 1024 thr = 16 waves; wave w: layer l=w>>2, unit-quarter uq=w&3.
// Phase p: layer l computes t=p-l; 1 barrier/phase; lds_h double-buffered.
//
// r8 vs r7 (VALU diet; schedule unchanged):
//  (1) lds_h relayout [buf][layer][laneIdx][6 uint2] (48B stride, 16B-aligned):
//      B-frag = ONE ds_read_b128 (uts 2s,2s+1 contiguous) -> no assembly movs;
//      48B stride keeps banks <=2-way. br/bw passed as literal constants ->
//      all LDS offsets fold to immediates on hoisted vaddrs.
//  (2) shared-rcp cell math: 14 trans/wave/phase (was 20).
__global__ __launch_bounds__(1024, 4)
void lstm_fused(const float* __restrict__ x0, float* __restrict__ last_out, WPtrs wp)
{
    const int tile = blockIdx.x;
    const int tid  = threadIdx.x;
    const int w    = tid >> 6;
    const int lane = tid & 63;
    const int l15  = lane & 15;
    const int l4   = lane >> 4;
    const int l    = w >> 2;
    const int uq   = w & 3;
    const bool hiH = (l15 >= 8);
    const int  col = l15 & 7;

    // [buf][layer][laneIdx][ut 0..3 + 2 pad] ; laneIdx = 16*l4 + col ; 24 KB
    __shared__ uint2 lds_h[2][4][64][6];

    for (int i = tid; i < 2 * 4 * 64 * 6; i += 1024)
        ((uint2*)lds_h)[i] = make_uint2(0u, 0u);

    const float* Wi = wp.Wi[l];
    const float* Wh = wp.Wh[l];

    // per-gate prescale: i,f,o -> log2e ; g -> 2*log2e
    const float gs[4] = {LOG2E, LOG2E, 2.0f * LOG2E, LOG2E};

    // ---- weight A-fragments (loop-invariant registers) ----
    // A-frag lane map (HW-verified): row = base + l15, k = 32*s + 4*l4 + j (+16 for j>=4)
    bf16x8 whA[4][2];
    bf16x8 wiA[4][2];
#pragma unroll
    for (int G = 0; G < 4; ++G) {
        const float sc = gs[G];
        const int row = G * 64 + 16 * uq + l15;
        const float* r = Wh + (size_t)row * 64;
#pragma unroll
        for (int s = 0; s < 2; ++s) {
            f32x4 a = *(const f32x4*)(r + 32 * s + 4 * l4);
            f32x4 b = *(const f32x4*)(r + 32 * s + 4 * l4 + 16);
            bf16x8 f;
            f[0] = (bf16_t)(a[0] * sc); f[1] = (bf16_t)(a[1] * sc);
            f[2] = (bf16_t)(a[2] * sc); f[3] = (bf16_t)(a[3] * sc);
            f[4] = (bf16_t)(b[0] * sc); f[5] = (bf16_t)(b[1] * sc);
            f[6] = (bf16_t)(b[2] * sc); f[7] = (bf16_t)(b[3] * sc);
            whA[G][s] = f;
        }
        if (l == 0) {
            const float* ri = Wi + (size_t)row * 18;     // K=18 padded to 32
            const int k0 = 4 * l4;
            bf16x8 f;
            f[0] = (bf16_t)(ri[k0 + 0] * sc); f[1] = (bf16_t)(ri[k0 + 1] * sc);
            f[2] = (bf16_t)(ri[k0 + 2] * sc); f[3] = (bf16_t)(ri[k0 + 3] * sc);
            f[4] = (l4 == 0) ? (bf16_t)(ri[16] * sc) : (bf16_t)0.0f;
            f[5] = (l4 == 0) ? (bf16_t)(ri[17] * sc) : (bf16_t)0.0f;
            f[6] = (bf16_t)0.0f; f[7] = (bf16_t)0.0f;
            wiA[G][0] = f;
            wiA[G][1] = f;   // placeholder; [2][1]/[3][1] become x buffers below
        } else {
            const float* ri = Wi + (size_t)row * 64;
#pragma unroll
            for (int s = 0; s < 2; ++s) {
                f32x4 a = *(const f32x4*)(ri + 32 * s + 4 * l4);
                f32x4 b = *(const f32x4*)(ri + 32 * s + 4 * l4 + 16);
                bf16x8 f;
                f[0] = (bf16_t)(a[0] * sc); f[1] = (bf16_t)(a[1] * sc);
                f[2] = (bf16_t)(a[2] * sc); f[3] = (bf16_t)(a[3] * sc);
                f[4] = (bf16_t)(b[0] * sc); f[5] = (bf16_t)(b[1] * sc);
                f[6] = (bf16_t)(b[2] * sc); f[7] = (bf16_t)(b[3] * sc);
                wiA[G][s] = f;
            }
        }
    }

    // ---- bias: ONLY the 8 post-swap scalars this lane consumes ----
    float biasA[4], biasB[4];
#pragma unroll
    for (int G = 0; G < 4; ++G) {
        const int rb = G * 64 + 16 * uq + 4 * l4 + (hiH ? 2 : 0);
        biasA[G] = (wp.bi[l][rb]     + wp.bh[l][rb])     * gs[G];
        biasB[G] = (wp.bi[l][rb + 1] + wp.bh[l][rb + 1]) * gs[G];
    }

    // ---- x prefetch (layer-0 waves), depth 2 ----
    // ALIASED onto wiA[2][1] / wiA[3][1]: dead slots for l==0, untouched by l>0.
    bf16x8& xfA = wiA[2][1];
    bf16x8& xfB = wiA[3][1];
    const int    xbatch = tile * 8 + (hiH ? 7 : col);
    const float* xrow   = x0 + (size_t)xbatch * (512 * 18);
    auto loadx = [&](int t, bf16x8& dst) {
        const float* xr = xrow + t * 18;
        const int k0 = 4 * l4;
        bf16x8 f;
        f[0] = (bf16_t)xr[k0 + 0]; f[1] = (bf16_t)xr[k0 + 1];
        f[2] = (bf16_t)xr[k0 + 2]; f[3] = (bf16_t)xr[k0 + 3];
        f[4] = (l4 == 0) ? (bf16_t)xr[16] : (bf16_t)0.0f;
        f[5] = (l4 == 0) ? (bf16_t)xr[17] : (bf16_t)0.0f;
        f[6] = (bf16_t)0.0f; f[7] = (bf16_t)0.0f;
        dst = f;
    };
    if (l == 0) { loadx(0, xfA); loadx(1, xfB); }

    float c0 = 0.0f, c1 = 0.0f;     // 2 real cells/lane

    __syncthreads();

    // br/bw arrive as LITERAL constants from the unrolled call sites.
    auto phase = [&](int p, int br, int bw, bf16x8& xf) {
        const int t = p - l;
        if (t >= 0 && t < 512) {
            const f32x4 z4 = {0.0f, 0.0f, 0.0f, 0.0f};
            f32x4 acc[4];

            // ---- x contribution (C starts at zero; bias added post-DPP) ----
            if (l == 0) {
#pragma unroll
                for (int G = 0; G < 4; ++G)
                    acc[G] = __builtin_amdgcn_mfma_f32_16x16x32_bf16(wiA[G][0], xf, z4, 0, 0, 0);
                loadx((t + 2) & 511, xf);       // prefetch 2 ahead (wrap harmless)
            } else {
                Frag b0, b1;
                {
                    uint4 q0 = *(const uint4*)&lds_h[br][l - 1][lane][0];
                    uint4 q1 = *(const uint4*)&lds_h[br][l - 1][lane][2];
                    b0.u[0] = q0.x; b0.u[1] = q0.y; b0.u[2] = q0.z; b0.u[3] = q0.w;
                    b1.u[0] = q1.x; b1.u[1] = q1.y; b1.u[2] = q1.z; b1.u[3] = q1.w;
                }
#pragma unroll
                for (int G = 0; G < 4; ++G)
                    acc[G] = __builtin_amdgcn_mfma_f32_16x16x32_bf16(wiA[G][0], b0.v, z4, 0, 0, 0);
#pragma unroll
                for (int G = 0; G < 4; ++G)
                    acc[G] = __builtin_amdgcn_mfma_f32_16x16x32_bf16(wiA[G][1], b1.v, acc[G], 0, 0, 0);
            }

            // ---- h contribution (own layer, t-1): 2 x ds_read_b128 ----
            {
                Frag h0, h1;
                uint4 q0 = *(const uint4*)&lds_h[br][l][lane][0];
                uint4 q1 = *(const uint4*)&lds_h[br][l][lane][2];
                h0.u[0] = q0.x; h0.u[1] = q0.y; h0.u[2] = q0.z; h0.u[3] = q0.w;
                h1.u[0] = q1.x; h1.u[1] = q1.y; h1.u[2] = q1.z; h1.u[3] = q1.w;
#pragma unroll
                for (int G = 0; G < 4; ++G)
                    acc[G] = __builtin_amdgcn_mfma_f32_16x16x32_bf16(whA[G][0], h0.v, acc[G], 0, 0, 0);
#pragma unroll
                for (int G = 0; G < 4; ++G)
                    acc[G] = __builtin_amdgcn_mfma_f32_16x16x32_bf16(whA[G][1], h1.v, acc[G], 0, 0, 0);
            }

            // ---- DPP half-swap: every lane gets 2 REAL cells; add bias here ----
            float g0[4], g1[4];
#pragma unroll
            for (int G = 0; G < 4; ++G) {
                const float s2 = dpp_halfswap(acc[G][2]);
                const float s3 = dpp_halfswap(acc[G][3]);
                g0[G] = (hiH ? s2 : acc[G][0]) + biasA[G];
                g1[G] = (hiH ? s3 : acc[G][1]) + biasB[G];
            }

            // ---- cell update (shared-rcp, prescaled gates) ----
            const float cA = cell_c(g0[0], g0[1], g0[2], c0);
            const float cB = cell_c(g1[0], g1[1], g1[2], c1);
            c0 = cA; c1 = cB;
            const float hA = cell_h(g0[3], cA);
            const float hB = cell_h(g1[3], cB);

            // ---- h writeback: one b32 per lane; pad laneIdx slots never written ----
            union { uint32_t u; bf16_t b[2]; } pk;
            pk.b[0] = (bf16_t)hA; pk.b[1] = (bf16_t)hB;
            uint32_t* slot = (uint32_t*)&lds_h[bw][l][16 * l4 + col][uq];
            slot[hiH ? 1 : 0] = pk.u;

            if (l == 3 && t == 511) {
                float* o = last_out + ((size_t)(tile * 8 + col)) * 64
                           + 16 * uq + 4 * l4 + (hiH ? 2 : 0);
                *(float2*)o = make_float2(hA, hB);
            }
        }
        __syncthreads();
    };

    // 515 phases needed (t=511 for l=3 at p=514); rounded up to 516.
    for (int p = 0; p < 516; p += 2) {
        phase(p,     1, 0, xfA);      // even p: read buf1, write buf0
        phase(p + 1, 0, 1, xfB);      // odd  p: read buf0, write buf1
    }
}

// out = relu(last @ W1^T + b1) @ W2^T + b2   (f32, tiny)
__global__ __launch_bounds__(256)
void mlp_head(const float* __restrict__ last,
              const float* __restrict__ W1, const float* __restrict__ b1,
              const float* __restrict__ W2, const float* __restrict__ b2,
              float* __restrict__ out)
{
    __shared__ float sW1[128 * 64];
    __shared__ float sb1[128];
    __shared__ float sW2[3 * 128];
    __shared__ float sb2[4];
    const int tid = threadIdx.x;
    for (int i = tid; i < 128 * 64; i += 256) sW1[i] = W1[i];
    for (int i = tid; i < 128; i += 256) sb1[i] = b1[i];
    for (int i = tid; i < 3 * 128; i += 256) sW2[i] = W2[i];
    if (tid < 3) sb2[tid] = b2[tid];
    __syncthreads();

    const int b = blockIdx.x * 256 + tid;
    const float* lb = last + (size_t)b * 64;
    float xv[64];
#pragma unroll
    for (int k = 0; k < 64; k += 4) {
        f32x4 v = *(const f32x4*)(lb + k);
        xv[k] = v[0]; xv[k + 1] = v[1]; xv[k + 2] = v[2]; xv[k + 3] = v[3];
    }
    float o0 = sb2[0], o1 = sb2[1], o2 = sb2[2];
    for (int j = 0; j < 128; ++j) {
        float a = sb1[j];
        const float* wr = &sW1[j * 64];
#pragma unroll
        for (int k = 0; k < 64; k += 4) {
            f32x4 wv = *(const f32x4*)(wr + k);
            a += xv[k] * wv[0] + xv[k + 1] * wv[1] + xv[k + 2] * wv[2] + xv[k + 3] * wv[3];
        }
        a = fmaxf(a, 0.0f);
        o0 += a * sW2[0 * 128 + j];
        o1 += a * sW2[1 * 128 + j];
        o2 += a * sW2[2 * 128 + j];
    }
    out[(size_t)b * 3 + 0] = o0;
    out[(size_t)b * 3 + 1] = o1;
    out[(size_t)b * 3 + 2] = o2;
}

extern "C" void kernel_launch(void* const* d_in, const int* in_sizes, int n_in,
                              void* d_out, int out_size, void* d_ws, size_t ws_size,
                              hipStream_t stream)
{
    (void)in_sizes; (void)n_in; (void)out_size; (void)ws_size;

    const float* x = (const float*)d_in[0];
    WPtrs wp;
    for (int l = 0; l < 4; ++l) {
        wp.Wi[l] = (const float*)d_in[1 + 4 * l + 0];
        wp.Wh[l] = (const float*)d_in[1 + 4 * l + 1];
        wp.bi[l] = (const float*)d_in[1 + 4 * l + 2];
        wp.bh[l] = (const float*)d_in[1 + 4 * l + 3];
    }
    const float* W1 = (const float*)d_in[17];
    const float* b1 = (const float*)d_in[18];
    const float* W2 = (const float*)d_in[19];
    const float* b2 = (const float*)d_in[20];

    float* last = (float*)d_ws;                 // 2048*64 f32 = 512 KiB

    lstm_fused<<<dim3(256), dim3(1024), 0, stream>>>(x, last, wp);
    mlp_head<<<dim3(8), dim3(256), 0, stream>>>(last, W1, b1, W2, b2, (float*)d_out);
}